// Round 1
// baseline (722.042 us; speedup 1.0000x reference)
//
#include <hip/hip_runtime.h>
#include <hip/hip_bf16.h>
#include <hip/hip_fp8.h>
#include <math.h>

#define Nn 20000
#define Ee 320000
#define Dd 512
#define Hh 4
#define Cc 256
#define Ll 4
#define Bb 16
#define HC 1024               // H*C
#define ETOT (Ee + Nn)        // edges + self loops = 340000
#define NEG_SLOPE 0.2f
#define LN_EPS 1e-5f
#define NBLK ((Nn + 255) / 256)   // 79 scan blocks

typedef __attribute__((ext_vector_type(8))) __bf16 bf16x8;
typedef __attribute__((ext_vector_type(4))) __bf16 bf16x4;
typedef __attribute__((ext_vector_type(4))) float f32x4;
typedef __attribute__((ext_vector_type(2))) float f32x2;

// fp8 e4m3 (OCP) x4 decode — HW packed cvt if available
__device__ __forceinline__ f32x4 fp8x4_to_f32(unsigned int v) {
#if __has_builtin(__builtin_amdgcn_cvt_pk_f32_fp8)
    f32x2 lo = __builtin_amdgcn_cvt_pk_f32_fp8((int)v, false);
    f32x2 hi = __builtin_amdgcn_cvt_pk_f32_fp8((int)v, true);
    f32x4 r; r[0] = lo[0]; r[1] = lo[1]; r[2] = hi[0]; r[3] = hi[1];
    return r;
#else
    f32x4 r;
    #pragma unroll
    for (int i = 0; i < 4; ++i) {
        __hip_fp8_e4m3 q; q.__x = (v >> (8 * i)) & 0xff;
        r[i] = (float)q;
    }
    return r;
#endif
}

__device__ __forceinline__ unsigned char f32_to_fp8(float f) {
    return __hip_fp8_e4m3(f).__x;
}

// ---------------- CSR build ----------------

__device__ __forceinline__ void decode_edge(const int* ei, int e, int& s, int& d) {
    if (e < Ee) { s = ei[e]; d = ei[Ee + e]; }
    else        { s = e - Ee; d = e - Ee; }   // self loop
}

__global__ void count_deg_kernel(const int* __restrict__ ei, int* __restrict__ deg) {
    int e = blockIdx.x * blockDim.x + threadIdx.x;
    if (e >= ETOT) return;
    int s, d; decode_edge(ei, e, s, d);
    atomicAdd(&deg[d], 1);
}

__global__ void scan1_kernel(const int* __restrict__ deg, int* __restrict__ tmp,
                             int* __restrict__ bsum) {
    __shared__ int sd[256];
    int tid = threadIdx.x;
    int i = blockIdx.x * 256 + tid;
    sd[tid] = (i < Nn) ? deg[i] : 0;
    __syncthreads();
    for (int off = 1; off < 256; off <<= 1) {
        int t = (tid >= off) ? sd[tid - off] : 0;
        __syncthreads();
        sd[tid] += t;
        __syncthreads();
    }
    if (i < Nn) tmp[i] = sd[tid];
    if (tid == 255) bsum[blockIdx.x] = sd[255];
}

__global__ void scan2_kernel(int* __restrict__ bsum) {   // single block, NBLK<=256
    __shared__ int sd[256];
    int tid = threadIdx.x;
    sd[tid] = (tid < NBLK) ? bsum[tid] : 0;
    __syncthreads();
    for (int off = 1; off < 256; off <<= 1) {
        int t = (tid >= off) ? sd[tid - off] : 0;
        __syncthreads();
        sd[tid] += t;
        __syncthreads();
    }
    if (tid < NBLK) bsum[tid] = sd[tid];
}

__global__ void scan3_kernel(const int* __restrict__ tmp, const int* __restrict__ bsum,
                             const int* __restrict__ deg,
                             int* __restrict__ row_ptr, int* __restrict__ cursor) {
    int i = blockIdx.x * 256 + threadIdx.x;
    if (i >= Nn) return;
    int boff = (blockIdx.x == 0) ? 0 : bsum[blockIdx.x - 1];
    int incl = tmp[i] + boff;
    row_ptr[i + 1] = incl;
    cursor[i] = incl - deg[i];
    if (i == 0) row_ptr[0] = 0;
}

__global__ void scatter_kernel(const int* __restrict__ ei, int* __restrict__ cursor,
                               int* __restrict__ csr_src) {
    int e = blockIdx.x * blockDim.x + threadIdx.x;
    if (e >= ETOT) return;
    int s, d; decode_edge(ei, e, s, d);
    int pos = atomicAdd(&cursor[d], 1);
    csr_src[pos] = s;
}

// ---------------- casts ----------------

__global__ void cast_kernel(const float* __restrict__ in, __bf16* __restrict__ out, int n4) {
    int i = blockIdx.x * blockDim.x + threadIdx.x;
    if (i >= n4) return;
    f32x4 v = ((const f32x4*)in)[i];
    bf16x4 o;
    #pragma unroll
    for (int k = 0; k < 4; ++k) o[k] = (__bf16)v[k];
    ((bf16x4*)out)[i] = o;
}

// W[K][N] fp32 -> WT[N][K] bf16; grid.z selects matrix (stride K*N)
__global__ void transpose_cast_kernel(const float* __restrict__ W, __bf16* __restrict__ WT,
                                      int K, int N) {
    __shared__ float tile[32][33];
    W  += (size_t)blockIdx.z * K * N;
    WT += (size_t)blockIdx.z * K * N;
    int n0 = blockIdx.x * 32, k0 = blockIdx.y * 32;
    for (int i = threadIdx.y; i < 32; i += 8)
        tile[i][threadIdx.x] = W[(size_t)(k0 + i) * N + n0 + threadIdx.x];
    __syncthreads();
    for (int i = threadIdx.y; i < 32; i += 8)
        WT[(size_t)(n0 + i) * K + k0 + threadIdx.x] = (__bf16)tile[threadIdx.x][i];
}

// ---------------- MFMA GEMM, 8-wave counted-vmcnt pipeline + fused alpha epilogue --------
// C8[M,1024](fp8) = A[M,K](bf16) @ BT[1024,K]^T.
// r15 rewrite: m97-style 2-barrier-drain structure (MfmaUtil 26%) -> T3+T4+T5
// counted-vmcnt phase schedule (guide §5.5; proven 45-62% MfmaUtil on gfx950).
// Geometry: BM=128 x BN=256, BK=64, 8 waves (512 thr), per-wave 64x64 (acc[4][4]
// identical to the previous verified kernel, incl. LDS 16B-group XOR swizzle and
// epilogue). 2 phases/K-tile (kp=0/1); each phase: {8 ds_read_b128 ; issue next
// tile's 3-load unit ; s_waitcnt vmcnt(3) ; s_barrier ; lgkmcnt(0)+sched_barrier
// (rule 18) ; setprio(1) ; 16 MFMA ; setprio(0) ; s_barrier}. vmcnt never drains
// to 0 in steady state (3 loads always in flight); vmcnt(0) only at last tile.
// Correctness: vmcnt retires in order (m135); unit u_kp(kt) is guaranteed by the
// previous phase's vmcnt(3)+barrier; buffer overwrite (tile kt+2 into buf read by
// kt) is separated by that tile's lgkmcnt(0)+second barrier (one-phase slack).
// Epilogue computes alpha partials from IN-REGISTER f32 h (zero extra traffic).
// Race-free partials: for fixed (row, head=cblk) the 4 writers are wn=0..3.

__device__ __forceinline__ void async16(const __bf16* g, __bf16* l) {
    __builtin_amdgcn_global_load_lds((const __attribute__((address_space(1))) void*)g,
                                     (__attribute__((address_space(3))) void*)l,
                                     16, 0, 0);
}

#define GEMM_PHASE(BUF, KP, DO_STAGE, KT_NEXT, VM_LAST)                                   \
  {                                                                                       \
    bf16x8 af[4], bv[4];                                                                  \
    _Pragma("unroll")                                                                     \
    for (int i = 0; i < 4; ++i) {                                                         \
        int row = waveRow + i * 16 + m16;                                                 \
        af[i] = *(const bf16x8*)&As[BUF][KP][row * 32 + ((quad ^ ((row >> 1) & 3)) << 3)];\
        int col = waveCol + i * 16 + m16;                                                 \
        bv[i] = *(const bf16x8*)&Bs[BUF][KP][col * 32 + ((quad ^ ((col >> 1) & 3)) << 3)];\
    }                                                                                     \
    if (DO_STAGE) {                                                                       \
        int kk = (KT_NEXT) * 64 + (KP) * 32;                                              \
        async16(A  + (size_t)gra  * K + kk + (gca << 3), &As[(BUF) ^ 1][KP][ldsA]);       \
        async16(BT + (size_t)grb  * K + kk + (gcb << 3), &Bs[(BUF) ^ 1][KP][ldsB]);       \
        async16(BT + (size_t)grb2 * K + kk + (gcb << 3), &Bs[(BUF) ^ 1][KP][ldsB2]);      \
    }                                                                                     \
    if (VM_LAST) { asm volatile("s_waitcnt vmcnt(0)" ::: "memory"); }                     \
    else         { asm volatile("s_waitcnt vmcnt(3)" ::: "memory"); }                     \
    __builtin_amdgcn_s_barrier();                                                         \
    asm volatile("s_waitcnt lgkmcnt(0)" ::: "memory");                                    \
    __builtin_amdgcn_sched_barrier(0);                                                    \
    __builtin_amdgcn_s_setprio(1);                                                        \
    _Pragma("unroll")                                                                     \
    for (int i = 0; i < 4; ++i)                                                           \
        _Pragma("unroll")                                                                 \
        for (int j = 0; j < 4; ++j)                                                       \
            acc[i][j] = __builtin_amdgcn_mfma_f32_16x16x32_bf16(af[i], bv[j],             \
                                                                acc[i][j], 0, 0, 0);      \
    __builtin_amdgcn_s_setprio(0);                                                        \
    __builtin_amdgcn_s_barrier();                                                         \
  }

__global__ __launch_bounds__(512) void mfma_gemm_kernel(
    const __bf16* __restrict__ A,   // [M][K]
    const __bf16* __restrict__ BT,  // [1024][K]
    unsigned char* __restrict__ C8, // [M][1024] fp8 e4m3 (agg gather payload)
    const float* __restrict__ att_s,  // [4][256] this layer
    const float* __restrict__ att_d,  // [4][256]
    float* __restrict__ aprt_s,     // [4][M][4] partials (race-free)
    float* __restrict__ aprt_d,     // [4][M][4]
    int M, int K)
{
    // XCD swizzle: all 4 col-blocks of a row-block share lin%8 -> same XCD
    // (A-tile fetched once per XCD; B total 2MB replicated in each XCD's L2).
    int lin = blockIdx.y * 4 + blockIdx.x;          // grid (4, 160) -> 640 ids
    int rblk = (lin >> 5) * 8 + (lin & 7);          // 0..159 (>=157 -> idle)
    int cblk = (lin >> 3) & 3;
    int rowBase = rblk * 128, colBase = cblk * 256;
    if (rowBase >= M) return;

    __shared__ __bf16 As[2][2][128 * 32];   // [dbuf][kp] 32KB
    __shared__ __bf16 Bs[2][2][256 * 32];   // [dbuf][kp] 64KB  (96KB total)
    int tid = threadIdx.x;
    int wave = tid >> 6, lane = tid & 63;
    int m16 = lane & 15, quad = lane >> 4;
    int wm = wave >> 2, wn = wave & 3;      // 2M x 4N wave grid
    int waveRow = wm * 64, waveCol = wn * 64;

    f32x4 acc[4][4] = {};

    // staging: thread t -> row t>>2, 16B chunk t&3 (per-wave-linear LDS dest;
    // swizzle applied on the GLOBAL source chunk, m173 pattern)
    int srow = tid >> 2;                    // 0..127
    int chk  = tid & 3;
    int gca  = chk ^ ((srow >> 1) & 3);     // same for srow+128 (128>>1 % 4 == 0)
    int gcb  = gca;
    int gra  = rowBase + srow;  if (gra >= M) gra = M - 1;
    int grb  = colBase + srow;              // BT rows always valid
    int grb2 = colBase + srow + 128;
    int ldsA  = srow * 32 + chk * 8;
    int ldsB  = srow * 32 + chk * 8;
    int ldsB2 = ldsB + 128 * 32;

    // prologue: stage both units of tile 0 (6 loads), retire unit kp0 only
    #pragma unroll
    for (int kp = 0; kp < 2; ++kp) {
        int kk = kp * 32;
        async16(A  + (size_t)gra  * K + kk + (gca << 3), &As[0][kp][ldsA]);
        async16(BT + (size_t)grb  * K + kk + (gcb << 3), &Bs[0][kp][ldsB]);
        async16(BT + (size_t)grb2 * K + kk + (gcb << 3), &Bs[0][kp][ldsB2]);
    }
    asm volatile("s_waitcnt vmcnt(3)" ::: "memory");
    __builtin_amdgcn_s_barrier();

    int NT = K >> 6;
    for (int kt = 0; kt < NT; ++kt) {
        int buf = kt & 1;
        bool more = (kt + 1 < NT);
        GEMM_PHASE(buf, 0, more, kt + 1, !more);   // reads u0(kt); guarantees u1(kt)
        GEMM_PHASE(buf, 1, more, kt + 1, false);   // reads u1(kt); guarantees u0(kt+1)
    }

    // att weights for this wave's 64-col span (single head: cblk == head)
    int cbase = colBase + waveCol;
    int head = cbase >> 8;                  // == cblk
    int part = wn;                          // 4 race-free writers per (row, head)
    float as4[4], ad4[4];
    #pragma unroll
    for (int j = 0; j < 4; ++j) {
        int off = (cbase + j * 16 + m16) & 255;
        as4[j] = att_s[head * 256 + off];
        ad4[j] = att_d[head * 256 + off];
    }

    // fp8 stores (C/D layout: col=lane&15, row=quad*4+reg) + alpha partials
    #pragma unroll
    for (int i = 0; i < 4; ++i) {
        int r0 = rowBase + waveRow + i * 16 + quad * 4;
        #pragma unroll
        for (int r = 0; r < 4; ++r) {
            int row = r0 + r;
            float ps = 0.f, pd = 0.f;
            #pragma unroll
            for (int j = 0; j < 4; ++j) {
                float h = acc[i][j][r];
                ps += h * as4[j];
                pd += h * ad4[j];
                if (row < M)
                    C8[(size_t)row * HC + cbase + j * 16 + m16] = f32_to_fp8(h);
            }
            #pragma unroll
            for (int off2 = 1; off2 < 16; off2 <<= 1) {
                ps += __shfl_xor(ps, off2);
                pd += __shfl_xor(pd, off2);
            }
            if (m16 == 0 && row < M) {
                aprt_s[((size_t)part * M + row) * 4 + head] = ps;
                aprt_d[((size_t)part * M + row) * 4 + head] = pd;
            }
        }
    }
}

// ---------------- alpha partial reduce: asrc/adst[n] = sum over 4 parts ----------------

__global__ void alpha_sum_kernel(const float* __restrict__ aprt_s,
                                 const float* __restrict__ aprt_d,
                                 float* __restrict__ asrc, float* __restrict__ adst) {
    int n = blockIdx.x * 256 + threadIdx.x;
    if (n >= Nn) return;
    f32x4 s = {0.f, 0.f, 0.f, 0.f}, d = {0.f, 0.f, 0.f, 0.f};
    #pragma unroll
    for (int p = 0; p < 4; ++p) {
        f32x4 vs = ((const f32x4*)aprt_s)[(size_t)p * Nn + n];
        f32x4 vd = ((const f32x4*)aprt_d)[(size_t)p * Nn + n];
        #pragma unroll
        for (int k = 0; k < 4; ++k) { s[k] += vs[k]; d[k] += vd[k]; }
    }
    ((f32x4*)asrc)[n] = s;
    ((f32x4*)adst)[n] = d;
}

// ---------------- edge-weight precompute (head-major output) ----------------

__global__ __launch_bounds__(256) void ew_kernel(const float* __restrict__ asrc,
                                                 const float* __restrict__ adst,
                                                 const int* __restrict__ row_ptr,
                                                 const int* __restrict__ csr_src,
                                                 float* __restrict__ ewT,
                                                 float* __restrict__ dinv) {
    int w = threadIdx.x >> 6, lane = threadIdx.x & 63;
    int n = blockIdx.x * 4 + w;
    if (n >= Nn) return;
    int start = row_ptr[n], end = row_ptr[n + 1];
    f32x4 ad = ((const f32x4*)adst)[n];
    f32x4 d = {0.f, 0.f, 0.f, 0.f};
    for (int e = start + lane; e < end; e += 64) {
        int s = csr_src[e];
        f32x4 as = ((const f32x4*)asrc)[s];
        #pragma unroll
        for (int k = 0; k < 4; ++k) {
            float z = as[k] + ad[k];
            z = (z > 0.f) ? z : NEG_SLOPE * z;
            float ex = __expf(z);
            ewT[(size_t)k * ETOT + e] = ex;
            d[k] += ex;
        }
    }
    #pragma unroll
    for (int off = 32; off > 0; off >>= 1) {
        #pragma unroll
        for (int k = 0; k < 4; ++k) d[k] += __shfl_down(d[k], off);
    }
    if (lane == 0) {
        f32x4 iv;
        #pragma unroll
        for (int k = 0; k < 4; ++k) iv[k] = 1.f / (d[k] + 1e-16f);
        ((f32x4*)dinv)[n] = iv;
    }
}

// ---------------- sliced aggregation (r11-proven: fp8, 8 ch/thread, 2-wide) ----------------
// grid (8, 1250): slice -> XCD affinity; per-XCD footprint 2.5MB (96% L2 hit, r10).
// Block = 16 node-slots x 16 ch-threads; each thread serially walks ITS node's
// edges for 8 fp8 channels (8B loads). No fused epilogue (r12/r13: latency-hiding loss).

__global__ __launch_bounds__(256) void agg_slice_kernel(
    const unsigned char* __restrict__ h8,
    const float* __restrict__ ewT,
    const float* __restrict__ dinv,
    const int* __restrict__ row_ptr,
    const int* __restrict__ csr_src,
    const float* __restrict__ bias_l,
    __bf16* __restrict__ outb)
{
    int slice = blockIdx.x;              // 0..7
    int head = slice >> 1;
    int tid = threadIdx.x;
    int nslot = tid >> 4;                // 0..15
    int ch = tid & 15;                   // 8B fp8 group within 128B slice
    int n = blockIdx.y * 16 + nslot;

    __shared__ int   csr_sh[512];
    __shared__ float ew_sh[512];
    __shared__ int   rp_sh[17];

    if (tid < 17) rp_sh[tid] = row_ptr[blockIdx.y * 16 + tid];
    __syncthreads();
    int blk_lo = rp_sh[0], blk_hi = rp_sh[16];
    int start = rp_sh[nslot], end = rp_sh[nslot + 1];

    const unsigned char* hs = h8 + slice * 128 + ch * 8;
    const float* ewh = ewT + (size_t)head * ETOT;
    float acc[8] = {};

    for (int c0 = blk_lo; c0 < blk_hi; c0 += 512) {
        int c1 = min(c0 + 512, blk_hi);
        int cnt = c1 - c0;
        for (int i = tid; i < cnt; i += 256) {     // coalesced stage
            csr_sh[i] = csr_src[c0 + i];
            ew_sh[i]  = ewh[c0 + i];
        }
        __syncthreads();
        int lo = max(start, c0), hi = min(end, c1);
        int e = lo;
        for (; e + 1 < hi; e += 2) {
            int s0 = csr_sh[e - c0], s1 = csr_sh[e + 1 - c0];
            float w0 = ew_sh[e - c0], w1 = ew_sh[e + 1 - c0];
            uint2 u0 = *(const uint2*)(hs + (size_t)s0 * HC);
            uint2 u1 = *(const uint2*)(hs + (size_t)s1 * HC);
            f32x4 a0 = fp8x4_to_f32(u0.x), b0 = fp8x4_to_f32(u0.y);
            f32x4 a1 = fp8x4_to_f32(u1.x), b1 = fp8x4_to_f32(u1.y);
            #pragma unroll
            for (int k = 0; k < 4; ++k) {
                acc[k]     += w0 * a0[k];
                acc[k + 4] += w0 * b0[k];
                acc[k]     += w1 * a1[k];
                acc[k + 4] += w1 * b1[k];
            }
        }
        if (e < hi) {
            int s0 = csr_sh[e - c0];
            float w0 = ew_sh[e - c0];
            uint2 u0 = *(const uint2*)(hs + (size_t)s0 * HC);
            f32x4 a0 = fp8x4_to_f32(u0.x), b0 = fp8x4_to_f32(u0.y);
            #pragma unroll
            for (int k = 0; k < 4; ++k) {
                acc[k]     += w0 * a0[k];
                acc[k + 4] += w0 * b0[k];
            }
        }
        __syncthreads();
    }

    float inv = dinv[n * 4 + head];
    bf16x8 o;
    #pragma unroll
    for (int k = 0; k < 8; ++k)
        o[k] = (__bf16)fmaxf(acc[k] * inv + bias_l[slice * 128 + ch * 8 + k], 0.f);
    *(bf16x8*)(outb + (size_t)n * HC + slice * 128 + ch * 8) = o;
}

// ---------------- global mean pool (race-free partials) ----------------

__device__ __forceinline__ int lower_bound_batch(const int* __restrict__ batch, int val) {
    int lo = 0, hi = Nn;
    while (lo < hi) { int mid = (lo + hi) >> 1; if (batch[mid] < val) lo = mid + 1; else hi = mid; }
    return lo;
}

__global__ void pool_kernel(const __bf16* __restrict__ h2b, const int* __restrict__ batch,
                            float* __restrict__ pooledP) {
    int b = blockIdx.x, part = blockIdx.y;   // grid (B, 8)
    int tid = threadIdx.x;
    int start = lower_bound_batch(batch, b);
    int end   = lower_bound_batch(batch, b + 1);
    int len = end - start;
    int chunk = (len + 7) / 8;
    int s0 = start + part * chunk;
    int s1 = min(s0 + chunk, end);
    float acc[4] = {0.f, 0.f, 0.f, 0.f};
    for (int n = s0; n < s1; ++n) {
        bf16x4 v = ((const bf16x4*)(h2b + (size_t)n * HC))[tid];
        #pragma unroll
        for (int k = 0; k < 4; ++k) acc[k] += (float)v[k];
    }
    #pragma unroll
    for (int k = 0; k < 4; ++k)
        pooledP[((size_t)part * Bb + b) * HC + tid * 4 + k] = acc[k];
}

// ---------------- projection (k-split, race-free partials) + layernorm ----------------

__global__ __launch_bounds__(512) void proj_partial_kernel(const float* __restrict__ pooledP,
                                                           const int* __restrict__ batch,
                                                           const float* __restrict__ projW,
                                                           float* __restrict__ projP) {
    int b = blockIdx.x, part = blockIdx.y;   // grid (16, 8)
    int d = threadIdx.x;                     // 512
    __shared__ float psum[HC];
    int start = lower_bound_batch(batch, b);
    int end   = lower_bound_batch(batch, b + 1);
    float inv = 1.0f / fmaxf((float)(end - start), 1.0f);
    for (int k = d; k < HC; k += 512) {
        float s = 0.f;
        #pragma unroll
        for (int p = 0; p < 8; ++p) s += pooledP[((size_t)p * Bb + b) * HC + k];
        psum[k] = s * inv;
    }
    __syncthreads();
    float acc = 0.f;
    int k0 = part * 128;
    for (int k = k0; k < k0 + 128; ++k)
        acc += psum[k] * projW[(size_t)k * Dd + d];
    projP[((size_t)part * Bb + b) * Dd + d] = acc;
}

__global__ __launch_bounds__(512) void ln_kernel(const float* __restrict__ projP,
                                                 const float* __restrict__ projb,
                                                 const float* __restrict__ gamma,
                                                 const float* __restrict__ beta,
                                                 float* __restrict__ out) {
    int b = blockIdx.x;
    int d = threadIdx.x;
    __shared__ float red[512];
    float o = projb[d];
    #pragma unroll
    for (int p = 0; p < 8; ++p) o += projP[((size_t)p * Bb + b) * Dd + d];
    red[d] = o;
    __syncthreads();
    for (int off = 256; off > 0; off >>= 1) {
        if (d < off) red[d] += red[d + off];
        __syncthreads();
    }
    float mu = red[0] / (float)Dd;
    __syncthreads();
    float df = o - mu;
    red[d] = df * df;
    __syncthreads();
    for (int off = 256; off > 0; off >>= 1) {
        if (d < off) red[d] += red[d + off];
        __syncthreads();
    }
    float var = red[0] / (float)Dd;
    out[b * Dd + d] = df / sqrtf(var + LN_EPS) * gamma[d] + beta[d];
}

// ---------------- launch ----------------

extern "C" void kernel_launch(void* const* d_in, const int* in_sizes, int n_in,
                              void* d_out, int out_size, void* d_ws, size_t ws_size,
                              hipStream_t stream) {
    const float* x         = (const float*)d_in[0];
    const int*   ei        = (const int*)d_in[1];
    const int*   batch     = (const int*)d_in[2];
    const float* W0        = (const float*)d_in[3];
    const float* W_rest    = (const float*)d_in[4];
    const float* att_src   = (const float*)d_in[5];
    const float* att_dst   = (const float*)d_in[6];
    const float* conv_bias = (const float*)d_in[7];
    const float* proj_W    = (const float*)d_in[8];
    const float* proj_b    = (const float*)d_in[9];
    const float* ln_gamma  = (const float*)d_in[10];
    const float* ln_beta   = (const float*)d_in[11];
    float* out = (float*)d_out;

    char* ws = (char*)d_ws;
    size_t off = 0;
    auto alloc = [&](size_t bytes) {
        void* p = ws + off;
        off = (off + bytes + 255) & ~(size_t)255;
        return p;
    };
    unsigned char* h8 = (unsigned char*)alloc((size_t)Nn * HC);   // GEMM out (fp8, agg payload)
    __bf16* h2b     = (__bf16*)alloc((size_t)Nn * HC * 2);        // layer out (bf16)
    __bf16* xb      = (__bf16*)alloc((size_t)Nn * Dd * 2);
    __bf16* W0T     = (__bf16*)alloc((size_t)HC * Dd * 2);
    __bf16* WrT     = (__bf16*)alloc((size_t)3 * HC * HC * 2);
    float*  aprt_s  = (float*)alloc((size_t)4 * Nn * Hh * 4);     // alpha partials
    float*  aprt_d  = (float*)alloc((size_t)4 * Nn * Hh * 4);
    float*  asrc    = (float*)alloc((size_t)Nn * Hh * 4);
    float*  adst    = (float*)alloc((size_t)Nn * Hh * 4);
    float*  ewT     = (float*)alloc((size_t)Hh * ETOT * 4);       // head-major
    float*  dinv    = (float*)alloc((size_t)Nn * Hh * 4);
    int*    deg     = (int*)alloc((size_t)Nn * 4);
    int*    tmp     = (int*)alloc((size_t)Nn * 4);
    int*    bsum    = (int*)alloc((size_t)256 * 4);
    int*    row_ptr = (int*)alloc((size_t)(Nn + 1) * 4);
    int*    cursor  = (int*)alloc((size_t)Nn * 4);
    int*    csr_src = (int*)alloc((size_t)ETOT * 4);
    float*  pooledP = (float*)alloc((size_t)8 * Bb * HC * 4);
    float*  projP   = (float*)alloc((size_t)8 * Bb * Dd * 4);
    (void)ws_size; (void)in_sizes; (void)n_in; (void)out_size;

    // ---- build CSR by destination ----
    hipMemsetAsync(deg, 0, (size_t)Nn * 4, stream);
    count_deg_kernel<<<(ETOT + 255) / 256, 256, 0, stream>>>(ei, deg);
    scan1_kernel<<<NBLK, 256, 0, stream>>>(deg, tmp, bsum);
    scan2_kernel<<<1, 256, 0, stream>>>(bsum);
    scan3_kernel<<<NBLK, 256, 0, stream>>>(tmp, bsum, deg, row_ptr, cursor);
    scatter_kernel<<<(ETOT + 255) / 256, 256, 0, stream>>>(ei, cursor, csr_src);

    // ---- bf16 casts / weight transposes ----
    cast_kernel<<<(Nn * Dd / 4 + 255) / 256, 256, 0, stream>>>(x, xb, Nn * Dd / 4);
    transpose_cast_kernel<<<dim3(HC / 32, Dd / 32, 1), dim3(32, 8), 0, stream>>>(W0, W0T, Dd, HC);
    transpose_cast_kernel<<<dim3(HC / 32, HC / 32, 3), dim3(32, 8), 0, stream>>>(W_rest, WrT, HC, HC);

    // ---- GAT layers ----
    dim3 gemm_grid(4, 160);   // 640 swizzled ids -> (157 row-blocks x 4 col-blocks)
    for (int l = 0; l < Ll; ++l) {
        const __bf16* Afeat = (l == 0) ? xb : h2b;
        int K = (l == 0) ? Dd : HC;
        const __bf16* BT = (l == 0) ? W0T : (WrT + (size_t)(l - 1) * HC * HC);
        mfma_gemm_kernel<<<gemm_grid, 512, 0, stream>>>(
            Afeat, BT, h8, att_src + l * HC, att_dst + l * HC, aprt_s, aprt_d, Nn, K);
        alpha_sum_kernel<<<NBLK, 256, 0, stream>>>(aprt_s, aprt_d, asrc, adst);
        ew_kernel<<<(Nn + 3) / 4, 256, 0, stream>>>(asrc, adst, row_ptr, csr_src, ewT, dinv);
        agg_slice_kernel<<<dim3(8, Nn / 16), 256, 0, stream>>>(
            h8, ewT, dinv, row_ptr, csr_src, conv_bias + l * HC, h2b);
    }

    // ---- pool + proj + layernorm (all race-free partials, no memsets) ----
    pool_kernel<<<dim3(Bb, 8), 256, 0, stream>>>(h2b, batch, pooledP);
    proj_partial_kernel<<<dim3(Bb, 8), 512, 0, stream>>>(pooledP, batch, proj_W, projP);
    ln_kernel<<<Bb, 512, 0, stream>>>(projP, proj_b, ln_gamma, ln_beta, out);
}

// Round 2
// 717.655 us; speedup vs baseline: 1.0061x; 1.0061x over previous
//
#include <hip/hip_runtime.h>
#include <hip/hip_bf16.h>
#include <hip/hip_fp8.h>
#include <math.h>

#define Nn 20000
#define Ee 320000
#define Dd 512
#define Hh 4
#define Cc 256
#define Ll 4
#define Bb 16
#define HC 1024               // H*C
#define ETOT (Ee + Nn)        // edges + self loops = 340000
#define NEG_SLOPE 0.2f
#define LN_EPS 1e-5f
#define NBLK ((Nn + 255) / 256)   // 79 scan blocks

typedef __attribute__((ext_vector_type(8))) __bf16 bf16x8;
typedef __attribute__((ext_vector_type(4))) __bf16 bf16x4;
typedef __attribute__((ext_vector_type(4))) float f32x4;
typedef __attribute__((ext_vector_type(2))) float f32x2;

// fp8 e4m3 (OCP) x4 decode — HW packed cvt if available
__device__ __forceinline__ f32x4 fp8x4_to_f32(unsigned int v) {
#if __has_builtin(__builtin_amdgcn_cvt_pk_f32_fp8)
    f32x2 lo = __builtin_amdgcn_cvt_pk_f32_fp8((int)v, false);
    f32x2 hi = __builtin_amdgcn_cvt_pk_f32_fp8((int)v, true);
    f32x4 r; r[0] = lo[0]; r[1] = lo[1]; r[2] = hi[0]; r[3] = hi[1];
    return r;
#else
    f32x4 r;
    #pragma unroll
    for (int i = 0; i < 4; ++i) {
        __hip_fp8_e4m3 q; q.__x = (v >> (8 * i)) & 0xff;
        r[i] = (float)q;
    }
    return r;
#endif
}

__device__ __forceinline__ unsigned char f32_to_fp8(float f) {
    return __hip_fp8_e4m3(f).__x;
}

// ---------------- CSR build ----------------

__device__ __forceinline__ void decode_edge(const int* ei, int e, int& s, int& d) {
    if (e < Ee) { s = ei[e]; d = ei[Ee + e]; }
    else        { s = e - Ee; d = e - Ee; }   // self loop
}

__global__ void count_deg_kernel(const int* __restrict__ ei, int* __restrict__ deg) {
    int e = blockIdx.x * blockDim.x + threadIdx.x;
    if (e >= ETOT) return;
    int s, d; decode_edge(ei, e, s, d);
    atomicAdd(&deg[d], 1);
}

__global__ void scan1_kernel(const int* __restrict__ deg, int* __restrict__ tmp,
                             int* __restrict__ bsum) {
    __shared__ int sd[256];
    int tid = threadIdx.x;
    int i = blockIdx.x * 256 + tid;
    sd[tid] = (i < Nn) ? deg[i] : 0;
    __syncthreads();
    for (int off = 1; off < 256; off <<= 1) {
        int t = (tid >= off) ? sd[tid - off] : 0;
        __syncthreads();
        sd[tid] += t;
        __syncthreads();
    }
    if (i < Nn) tmp[i] = sd[tid];
    if (tid == 255) bsum[blockIdx.x] = sd[255];
}

__global__ void scan2_kernel(int* __restrict__ bsum) {   // single block, NBLK<=256
    __shared__ int sd[256];
    int tid = threadIdx.x;
    sd[tid] = (tid < NBLK) ? bsum[tid] : 0;
    __syncthreads();
    for (int off = 1; off < 256; off <<= 1) {
        int t = (tid >= off) ? sd[tid - off] : 0;
        __syncthreads();
        sd[tid] += t;
        __syncthreads();
    }
    if (tid < NBLK) bsum[tid] = sd[tid];
}

__global__ void scan3_kernel(const int* __restrict__ tmp, const int* __restrict__ bsum,
                             const int* __restrict__ deg,
                             int* __restrict__ row_ptr, int* __restrict__ cursor) {
    int i = blockIdx.x * 256 + threadIdx.x;
    if (i >= Nn) return;
    int boff = (blockIdx.x == 0) ? 0 : bsum[blockIdx.x - 1];
    int incl = tmp[i] + boff;
    row_ptr[i + 1] = incl;
    cursor[i] = incl - deg[i];
    if (i == 0) row_ptr[0] = 0;
}

__global__ void scatter_kernel(const int* __restrict__ ei, int* __restrict__ cursor,
                               int* __restrict__ csr_src) {
    int e = blockIdx.x * blockDim.x + threadIdx.x;
    if (e >= ETOT) return;
    int s, d; decode_edge(ei, e, s, d);
    int pos = atomicAdd(&cursor[d], 1);
    csr_src[pos] = s;
}

// ---------------- casts ----------------

__global__ void cast_kernel(const float* __restrict__ in, __bf16* __restrict__ out, int n4) {
    int i = blockIdx.x * blockDim.x + threadIdx.x;
    if (i >= n4) return;
    f32x4 v = ((const f32x4*)in)[i];
    bf16x4 o;
    #pragma unroll
    for (int k = 0; k < 4; ++k) o[k] = (__bf16)v[k];
    ((bf16x4*)out)[i] = o;
}

// W[K][N] fp32 -> WT[N][K] bf16; grid.z selects matrix (stride K*N)
__global__ void transpose_cast_kernel(const float* __restrict__ W, __bf16* __restrict__ WT,
                                      int K, int N) {
    __shared__ float tile[32][33];
    W  += (size_t)blockIdx.z * K * N;
    WT += (size_t)blockIdx.z * K * N;
    int n0 = blockIdx.x * 32, k0 = blockIdx.y * 32;
    for (int i = threadIdx.y; i < 32; i += 8)
        tile[i][threadIdx.x] = W[(size_t)(k0 + i) * N + n0 + threadIdx.x];
    __syncthreads();
    for (int i = threadIdx.y; i < 32; i += 8)
        WT[(size_t)(n0 + i) * K + k0 + threadIdx.x] = (__bf16)tile[threadIdx.x][i];
}

// ---------------- MFMA GEMM, 8-wave DEEP counted-vmcnt pipeline + fused epilogue --------
// C8[M,1024](fp8) = A[M,K](bf16) @ BT[1024,K]^T.
// r16: r15's phase skeleton was verified-correct but had load->wait distance of
// ONE phase (vmcnt(3) waited on loads issued in the previous phase) => every
// phase stalled ~HBM latency (MfmaUtil 17%). Fix = pipeline DEPTH, not structure:
//   - TRIPLE-buffered K-tiles (LDS 144KB, still 1 block/CU)
//   - phase (kt,kp) stages tile kt+2 => load->wait distance 2-3 phases (>1200cy)
//   - steady-state wait vmcnt(9) (3 loads/phase x 3 newer phases in flight)
//   - exact tail counts 6/3/0 (counted waits must be exact to actually wait)
// Phase = {8x ds_read_b128 ; stage 3 async16 ; s_waitcnt vmcnt(N) ; s_barrier ;
//          lgkmcnt(0)+sched_barrier (rule 18) ; setprio(1) 16 MFMA setprio(0) ;
//          s_barrier}.
// Safety: buffer (kt+2)%3 staged at (kt,0) was last ds_read in tile kt-1; those
// reads retire at that phase's lgkmcnt(0), before its end-barrier, which precedes
// the staging issue. vmcnt retires in order (m135), so counted waits are exact.
// Epilogue computes alpha partials from IN-REGISTER f32 h (zero extra traffic).
// Race-free partials: for fixed (row, head=cblk) the 4 writers are wn=0..3.

__device__ __forceinline__ void async16(const __bf16* g, __bf16* l) {
    __builtin_amdgcn_global_load_lds((const __attribute__((address_space(1))) void*)g,
                                     (__attribute__((address_space(3))) void*)l,
                                     16, 0, 0);
}

#define GEMM_PHASE(BUFI, BUFN, KP, DO_STAGE, KT_NEXT, VMSTR)                              \
  {                                                                                       \
    bf16x8 af[4], bv[4];                                                                  \
    _Pragma("unroll")                                                                     \
    for (int i = 0; i < 4; ++i) {                                                         \
        int row = waveRow + i * 16 + m16;                                                 \
        af[i] = *(const bf16x8*)&As[BUFI][KP][row * 32 + ((quad ^ ((row >> 1) & 3)) << 3)];\
        int col = waveCol + i * 16 + m16;                                                 \
        bv[i] = *(const bf16x8*)&Bs[BUFI][KP][col * 32 + ((quad ^ ((col >> 1) & 3)) << 3)];\
    }                                                                                     \
    if (DO_STAGE) {                                                                       \
        int kk = (KT_NEXT) * 64 + (KP) * 32;                                              \
        async16(A  + (size_t)gra  * K + kk + (gca << 3), &As[BUFN][KP][ldsA]);            \
        async16(BT + (size_t)grb  * K + kk + (gcb << 3), &Bs[BUFN][KP][ldsB]);            \
        async16(BT + (size_t)grb2 * K + kk + (gcb << 3), &Bs[BUFN][KP][ldsB2]);           \
    }                                                                                     \
    asm volatile("s_waitcnt " VMSTR ::: "memory");                                        \
    __builtin_amdgcn_s_barrier();                                                         \
    asm volatile("s_waitcnt lgkmcnt(0)" ::: "memory");                                    \
    __builtin_amdgcn_sched_barrier(0);                                                    \
    __builtin_amdgcn_s_setprio(1);                                                        \
    _Pragma("unroll")                                                                     \
    for (int i = 0; i < 4; ++i)                                                           \
        _Pragma("unroll")                                                                 \
        for (int j = 0; j < 4; ++j)                                                       \
            acc[i][j] = __builtin_amdgcn_mfma_f32_16x16x32_bf16(af[i], bv[j],             \
                                                                acc[i][j], 0, 0, 0);      \
    __builtin_amdgcn_s_setprio(0);                                                        \
    __builtin_amdgcn_s_barrier();                                                         \
  }

__global__ __launch_bounds__(512) void mfma_gemm_kernel(
    const __bf16* __restrict__ A,   // [M][K]
    const __bf16* __restrict__ BT,  // [1024][K]
    unsigned char* __restrict__ C8, // [M][1024] fp8 e4m3 (agg gather payload)
    const float* __restrict__ att_s,  // [4][256] this layer
    const float* __restrict__ att_d,  // [4][256]
    float* __restrict__ aprt_s,     // [4][M][4] partials (race-free)
    float* __restrict__ aprt_d,     // [4][M][4]
    int M, int K)
{
    // XCD swizzle: all 4 col-blocks of a row-block share lin%8 -> same XCD
    // (A-tile fetched once per XCD; B total 2MB replicated in each XCD's L2).
    int lin = blockIdx.y * 4 + blockIdx.x;          // grid (4, 160) -> 640 ids
    int rblk = (lin >> 5) * 8 + (lin & 7);          // 0..159 (>=157 -> idle)
    int cblk = (lin >> 3) & 3;
    int rowBase = rblk * 128, colBase = cblk * 256;
    if (rowBase >= M) return;

    __shared__ __bf16 As[3][2][128 * 32];   // [3buf][kp] 48KB
    __shared__ __bf16 Bs[3][2][256 * 32];   // [3buf][kp] 96KB  (144KB total)
    int tid = threadIdx.x;
    int wave = tid >> 6, lane = tid & 63;
    int m16 = lane & 15, quad = lane >> 4;
    int wm = wave >> 2, wn = wave & 3;      // 2M x 4N wave grid
    int waveRow = wm * 64, waveCol = wn * 64;

    f32x4 acc[4][4] = {};

    // staging: thread t -> row t>>2, 16B chunk t&3 (per-wave-linear LDS dest;
    // swizzle applied on the GLOBAL source chunk, m173 pattern)
    int srow = tid >> 2;                    // 0..127
    int chk  = tid & 3;
    int gca  = chk ^ ((srow >> 1) & 3);     // same for srow+128 (128>>1 % 4 == 0)
    int gcb  = gca;
    int gra  = rowBase + srow;  if (gra >= M) gra = M - 1;
    int grb  = colBase + srow;              // BT rows always valid
    int grb2 = colBase + srow + 128;
    int ldsA  = srow * 32 + chk * 8;
    int ldsB  = srow * 32 + chk * 8;
    int ldsB2 = ldsB + 128 * 32;

    // prologue: stage tiles 0 and 1 (12 loads); retire only u(0,0) (allow 9 newer)
    #pragma unroll
    for (int kt = 0; kt < 2; ++kt)
        #pragma unroll
        for (int kp = 0; kp < 2; ++kp) {
            int kk = kt * 64 + kp * 32;
            async16(A  + (size_t)gra  * K + kk + (gca << 3), &As[kt][kp][ldsA]);
            async16(BT + (size_t)grb  * K + kk + (gcb << 3), &Bs[kt][kp][ldsB]);
            async16(BT + (size_t)grb2 * K + kk + (gcb << 3), &Bs[kt][kp][ldsB2]);
        }
    asm volatile("s_waitcnt vmcnt(9)" ::: "memory");
    __builtin_amdgcn_s_barrier();

    int NT = K >> 6;                        // 8 (K=512) or 16 (K=1024), NT>=3
    int bufi = 0;
    for (int kt = 0; kt + 2 < NT; ++kt) {
        int bufn = (bufi == 0) ? 2 : bufi - 1;   // (bufi+2)%3
        GEMM_PHASE(bufi, bufn, 0, true, kt + 2, "vmcnt(9)");
        GEMM_PHASE(bufi, bufn, 1, true, kt + 2, "vmcnt(9)");
        bufi = (bufi == 2) ? 0 : bufi + 1;
    }
    // kt = NT-2: nothing left to stage; exact tail counts
    GEMM_PHASE(bufi, 0, 0, false, 0, "vmcnt(6)");
    GEMM_PHASE(bufi, 0, 1, false, 0, "vmcnt(3)");
    bufi = (bufi == 2) ? 0 : bufi + 1;
    // kt = NT-1
    GEMM_PHASE(bufi, 0, 0, false, 0, "vmcnt(0)");
    GEMM_PHASE(bufi, 0, 1, false, 0, "vmcnt(0)");

    // att weights for this wave's 64-col span (single head: cblk == head)
    int cbase = colBase + waveCol;
    int head = cbase >> 8;                  // == cblk
    int part = wn;                          // 4 race-free writers per (row, head)
    float as4[4], ad4[4];
    #pragma unroll
    for (int j = 0; j < 4; ++j) {
        int off = (cbase + j * 16 + m16) & 255;
        as4[j] = att_s[head * 256 + off];
        ad4[j] = att_d[head * 256 + off];
    }

    // fp8 stores (C/D layout: col=lane&15, row=quad*4+reg) + alpha partials
    #pragma unroll
    for (int i = 0; i < 4; ++i) {
        int r0 = rowBase + waveRow + i * 16 + quad * 4;
        #pragma unroll
        for (int r = 0; r < 4; ++r) {
            int row = r0 + r;
            float ps = 0.f, pd = 0.f;
            #pragma unroll
            for (int j = 0; j < 4; ++j) {
                float h = acc[i][j][r];
                ps += h * as4[j];
                pd += h * ad4[j];
                if (row < M)
                    C8[(size_t)row * HC + cbase + j * 16 + m16] = f32_to_fp8(h);
            }
            #pragma unroll
            for (int off2 = 1; off2 < 16; off2 <<= 1) {
                ps += __shfl_xor(ps, off2);
                pd += __shfl_xor(pd, off2);
            }
            if (m16 == 0 && row < M) {
                aprt_s[((size_t)part * M + row) * 4 + head] = ps;
                aprt_d[((size_t)part * M + row) * 4 + head] = pd;
            }
        }
    }
}

// ---------------- alpha partial reduce: asrc/adst[n] = sum over 4 parts ----------------

__global__ void alpha_sum_kernel(const float* __restrict__ aprt_s,
                                 const float* __restrict__ aprt_d,
                                 float* __restrict__ asrc, float* __restrict__ adst) {
    int n = blockIdx.x * 256 + threadIdx.x;
    if (n >= Nn) return;
    f32x4 s = {0.f, 0.f, 0.f, 0.f}, d = {0.f, 0.f, 0.f, 0.f};
    #pragma unroll
    for (int p = 0; p < 4; ++p) {
        f32x4 vs = ((const f32x4*)aprt_s)[(size_t)p * Nn + n];
        f32x4 vd = ((const f32x4*)aprt_d)[(size_t)p * Nn + n];
        #pragma unroll
        for (int k = 0; k < 4; ++k) { s[k] += vs[k]; d[k] += vd[k]; }
    }
    ((f32x4*)asrc)[n] = s;
    ((f32x4*)adst)[n] = d;
}

// ---------------- edge-weight precompute (head-major output) ----------------

__global__ __launch_bounds__(256) void ew_kernel(const float* __restrict__ asrc,
                                                 const float* __restrict__ adst,
                                                 const int* __restrict__ row_ptr,
                                                 const int* __restrict__ csr_src,
                                                 float* __restrict__ ewT,
                                                 float* __restrict__ dinv) {
    int w = threadIdx.x >> 6, lane = threadIdx.x & 63;
    int n = blockIdx.x * 4 + w;
    if (n >= Nn) return;
    int start = row_ptr[n], end = row_ptr[n + 1];
    f32x4 ad = ((const f32x4*)adst)[n];
    f32x4 d = {0.f, 0.f, 0.f, 0.f};
    for (int e = start + lane; e < end; e += 64) {
        int s = csr_src[e];
        f32x4 as = ((const f32x4*)asrc)[s];
        #pragma unroll
        for (int k = 0; k < 4; ++k) {
            float z = as[k] + ad[k];
            z = (z > 0.f) ? z : NEG_SLOPE * z;
            float ex = __expf(z);
            ewT[(size_t)k * ETOT + e] = ex;
            d[k] += ex;
        }
    }
    #pragma unroll
    for (int off = 32; off > 0; off >>= 1) {
        #pragma unroll
        for (int k = 0; k < 4; ++k) d[k] += __shfl_down(d[k], off);
    }
    if (lane == 0) {
        f32x4 iv;
        #pragma unroll
        for (int k = 0; k < 4; ++k) iv[k] = 1.f / (d[k] + 1e-16f);
        ((f32x4*)dinv)[n] = iv;
    }
}

// ---------------- sliced aggregation (r11-proven: fp8, 8 ch/thread, 2-wide) ----------------
// grid (8, 1250): slice -> XCD affinity; per-XCD footprint 2.5MB (96% L2 hit, r10).
// Block = 16 node-slots x 16 ch-threads; each thread serially walks ITS node's
// edges for 8 fp8 channels (8B loads). No fused epilogue (r12/r13: latency-hiding loss).

__global__ __launch_bounds__(256) void agg_slice_kernel(
    const unsigned char* __restrict__ h8,
    const float* __restrict__ ewT,
    const float* __restrict__ dinv,
    const int* __restrict__ row_ptr,
    const int* __restrict__ csr_src,
    const float* __restrict__ bias_l,
    __bf16* __restrict__ outb)
{
    int slice = blockIdx.x;              // 0..7
    int head = slice >> 1;
    int tid = threadIdx.x;
    int nslot = tid >> 4;                // 0..15
    int ch = tid & 15;                   // 8B fp8 group within 128B slice
    int n = blockIdx.y * 16 + nslot;

    __shared__ int   csr_sh[512];
    __shared__ float ew_sh[512];
    __shared__ int   rp_sh[17];

    if (tid < 17) rp_sh[tid] = row_ptr[blockIdx.y * 16 + tid];
    __syncthreads();
    int blk_lo = rp_sh[0], blk_hi = rp_sh[16];
    int start = rp_sh[nslot], end = rp_sh[nslot + 1];

    const unsigned char* hs = h8 + slice * 128 + ch * 8;
    const float* ewh = ewT + (size_t)head * ETOT;
    float acc[8] = {};

    for (int c0 = blk_lo; c0 < blk_hi; c0 += 512) {
        int c1 = min(c0 + 512, blk_hi);
        int cnt = c1 - c0;
        for (int i = tid; i < cnt; i += 256) {     // coalesced stage
            csr_sh[i] = csr_src[c0 + i];
            ew_sh[i]  = ewh[c0 + i];
        }
        __syncthreads();
        int lo = max(start, c0), hi = min(end, c1);
        int e = lo;
        for (; e + 1 < hi; e += 2) {
            int s0 = csr_sh[e - c0], s1 = csr_sh[e + 1 - c0];
            float w0 = ew_sh[e - c0], w1 = ew_sh[e + 1 - c0];
            uint2 u0 = *(const uint2*)(hs + (size_t)s0 * HC);
            uint2 u1 = *(const uint2*)(hs + (size_t)s1 * HC);
            f32x4 a0 = fp8x4_to_f32(u0.x), b0 = fp8x4_to_f32(u0.y);
            f32x4 a1 = fp8x4_to_f32(u1.x), b1 = fp8x4_to_f32(u1.y);
            #pragma unroll
            for (int k = 0; k < 4; ++k) {
                acc[k]     += w0 * a0[k];
                acc[k + 4] += w0 * b0[k];
                acc[k]     += w1 * a1[k];
                acc[k + 4] += w1 * b1[k];
            }
        }
        if (e < hi) {
            int s0 = csr_sh[e - c0];
            float w0 = ew_sh[e - c0];
            uint2 u0 = *(const uint2*)(hs + (size_t)s0 * HC);
            f32x4 a0 = fp8x4_to_f32(u0.x), b0 = fp8x4_to_f32(u0.y);
            #pragma unroll
            for (int k = 0; k < 4; ++k) {
                acc[k]     += w0 * a0[k];
                acc[k + 4] += w0 * b0[k];
            }
        }
        __syncthreads();
    }

    float inv = dinv[n * 4 + head];
    bf16x8 o;
    #pragma unroll
    for (int k = 0; k < 8; ++k)
        o[k] = (__bf16)fmaxf(acc[k] * inv + bias_l[slice * 128 + ch * 8 + k], 0.f);
    *(bf16x8*)(outb + (size_t)n * HC + slice * 128 + ch * 8) = o;
}

// ---------------- global mean pool (race-free partials) ----------------

__device__ __forceinline__ int lower_bound_batch(const int* __restrict__ batch, int val) {
    int lo = 0, hi = Nn;
    while (lo < hi) { int mid = (lo + hi) >> 1; if (batch[mid] < val) lo = mid + 1; else hi = mid; }
    return lo;
}

__global__ void pool_kernel(const __bf16* __restrict__ h2b, const int* __restrict__ batch,
                            float* __restrict__ pooledP) {
    int b = blockIdx.x, part = blockIdx.y;   // grid (B, 8)
    int tid = threadIdx.x;
    int start = lower_bound_batch(batch, b);
    int end   = lower_bound_batch(batch, b + 1);
    int len = end - start;
    int chunk = (len + 7) / 8;
    int s0 = start + part * chunk;
    int s1 = min(s0 + chunk, end);
    float acc[4] = {0.f, 0.f, 0.f, 0.f};
    for (int n = s0; n < s1; ++n) {
        bf16x4 v = ((const bf16x4*)(h2b + (size_t)n * HC))[tid];
        #pragma unroll
        for (int k = 0; k < 4; ++k) acc[k] += (float)v[k];
    }
    #pragma unroll
    for (int k = 0; k < 4; ++k)
        pooledP[((size_t)part * Bb + b) * HC + tid * 4 + k] = acc[k];
}

// ---------------- projection (k-split, race-free partials) + layernorm ----------------

__global__ __launch_bounds__(512) void proj_partial_kernel(const float* __restrict__ pooledP,
                                                           const int* __restrict__ batch,
                                                           const float* __restrict__ projW,
                                                           float* __restrict__ projP) {
    int b = blockIdx.x, part = blockIdx.y;   // grid (16, 8)
    int d = threadIdx.x;                     // 512
    __shared__ float psum[HC];
    int start = lower_bound_batch(batch, b);
    int end   = lower_bound_batch(batch, b + 1);
    float inv = 1.0f / fmaxf((float)(end - start), 1.0f);
    for (int k = d; k < HC; k += 512) {
        float s = 0.f;
        #pragma unroll
        for (int p = 0; p < 8; ++p) s += pooledP[((size_t)p * Bb + b) * HC + k];
        psum[k] = s * inv;
    }
    __syncthreads();
    float acc = 0.f;
    int k0 = part * 128;
    for (int k = k0; k < k0 + 128; ++k)
        acc += psum[k] * projW[(size_t)k * Dd + d];
    projP[((size_t)part * Bb + b) * Dd + d] = acc;
}

__global__ __launch_bounds__(512) void ln_kernel(const float* __restrict__ projP,
                                                 const float* __restrict__ projb,
                                                 const float* __restrict__ gamma,
                                                 const float* __restrict__ beta,
                                                 float* __restrict__ out) {
    int b = blockIdx.x;
    int d = threadIdx.x;
    __shared__ float red[512];
    float o = projb[d];
    #pragma unroll
    for (int p = 0; p < 8; ++p) o += projP[((size_t)p * Bb + b) * Dd + d];
    red[d] = o;
    __syncthreads();
    for (int off = 256; off > 0; off >>= 1) {
        if (d < off) red[d] += red[d + off];
        __syncthreads();
    }
    float mu = red[0] / (float)Dd;
    __syncthreads();
    float df = o - mu;
    red[d] = df * df;
    __syncthreads();
    for (int off = 256; off > 0; off >>= 1) {
        if (d < off) red[d] += red[d + off];
        __syncthreads();
    }
    float var = red[0] / (float)Dd;
    out[b * Dd + d] = df / sqrtf(var + LN_EPS) * gamma[d] + beta[d];
}

// ---------------- launch ----------------

extern "C" void kernel_launch(void* const* d_in, const int* in_sizes, int n_in,
                              void* d_out, int out_size, void* d_ws, size_t ws_size,
                              hipStream_t stream) {
    const float* x         = (const float*)d_in[0];
    const int*   ei        = (const int*)d_in[1];
    const int*   batch     = (const int*)d_in[2];
    const float* W0        = (const float*)d_in[3];
    const float* W_rest    = (const float*)d_in[4];
    const float* att_src   = (const float*)d_in[5];
    const float* att_dst   = (const float*)d_in[6];
    const float* conv_bias = (const float*)d_in[7];
    const float* proj_W    = (const float*)d_in[8];
    const float* proj_b    = (const float*)d_in[9];
    const float* ln_gamma  = (const float*)d_in[10];
    const float* ln_beta   = (const float*)d_in[11];
    float* out = (float*)d_out;

    char* ws = (char*)d_ws;
    size_t off = 0;
    auto alloc = [&](size_t bytes) {
        void* p = ws + off;
        off = (off + bytes + 255) & ~(size_t)255;
        return p;
    };
    unsigned char* h8 = (unsigned char*)alloc((size_t)Nn * HC);   // GEMM out (fp8, agg payload)
    __bf16* h2b     = (__bf16*)alloc((size_t)Nn * HC * 2);        // layer out (bf16)
    __bf16* xb      = (__bf16*)alloc((size_t)Nn * Dd * 2);
    __bf16* W0T     = (__bf16*)alloc((size_t)HC * Dd * 2);
    __bf16* WrT     = (__bf16*)alloc((size_t)3 * HC * HC * 2);
    float*  aprt_s  = (float*)alloc((size_t)4 * Nn * Hh * 4);     // alpha partials
    float*  aprt_d  = (float*)alloc((size_t)4 * Nn * Hh * 4);
    float*  asrc    = (float*)alloc((size_t)Nn * Hh * 4);
    float*  adst    = (float*)alloc((size_t)Nn * Hh * 4);
    float*  ewT     = (float*)alloc((size_t)Hh * ETOT * 4);       // head-major
    float*  dinv    = (float*)alloc((size_t)Nn * Hh * 4);
    int*    deg     = (int*)alloc((size_t)Nn * 4);
    int*    tmp     = (int*)alloc((size_t)Nn * 4);
    int*    bsum    = (int*)alloc((size_t)256 * 4);
    int*    row_ptr = (int*)alloc((size_t)(Nn + 1) * 4);
    int*    cursor  = (int*)alloc((size_t)Nn * 4);
    int*    csr_src = (int*)alloc((size_t)ETOT * 4);
    float*  pooledP = (float*)alloc((size_t)8 * Bb * HC * 4);
    float*  projP   = (float*)alloc((size_t)8 * Bb * Dd * 4);
    (void)ws_size; (void)in_sizes; (void)n_in; (void)out_size;

    // ---- build CSR by destination ----
    hipMemsetAsync(deg, 0, (size_t)Nn * 4, stream);
    count_deg_kernel<<<(ETOT + 255) / 256, 256, 0, stream>>>(ei, deg);
    scan1_kernel<<<NBLK, 256, 0, stream>>>(deg, tmp, bsum);
    scan2_kernel<<<1, 256, 0, stream>>>(bsum);
    scan3_kernel<<<NBLK, 256, 0, stream>>>(tmp, bsum, deg, row_ptr, cursor);
    scatter_kernel<<<(ETOT + 255) / 256, 256, 0, stream>>>(ei, cursor, csr_src);

    // ---- bf16 casts / weight transposes ----
    cast_kernel<<<(Nn * Dd / 4 + 255) / 256, 256, 0, stream>>>(x, xb, Nn * Dd / 4);
    transpose_cast_kernel<<<dim3(HC / 32, Dd / 32, 1), dim3(32, 8), 0, stream>>>(W0, W0T, Dd, HC);
    transpose_cast_kernel<<<dim3(HC / 32, HC / 32, 3), dim3(32, 8), 0, stream>>>(W_rest, WrT, HC, HC);

    // ---- GAT layers ----
    dim3 gemm_grid(4, 160);   // 640 swizzled ids -> (157 row-blocks x 4 col-blocks)
    for (int l = 0; l < Ll; ++l) {
        const __bf16* Afeat = (l == 0) ? xb : h2b;
        int K = (l == 0) ? Dd : HC;
        const __bf16* BT = (l == 0) ? W0T : (WrT + (size_t)(l - 1) * HC * HC);
        mfma_gemm_kernel<<<gemm_grid, 512, 0, stream>>>(
            Afeat, BT, h8, att_src + l * HC, att_dst + l * HC, aprt_s, aprt_d, Nn, K);
        alpha_sum_kernel<<<NBLK, 256, 0, stream>>>(aprt_s, aprt_d, asrc, adst);
        ew_kernel<<<(Nn + 3) / 4, 256, 0, stream>>>(asrc, adst, row_ptr, csr_src, ewT, dinv);
        agg_slice_kernel<<<dim3(8, Nn / 16), 256, 0, stream>>>(
            h8, ewT, dinv, row_ptr, csr_src, conv_bias + l * HC, h2b);
    }

    // ---- pool + proj + layernorm (all race-free partials, no memsets) ----
    pool_kernel<<<dim3(Bb, 8), 256, 0, stream>>>(h2b, batch, pooledP);
    proj_partial_kernel<<<dim3(Bb, 8), 512, 0, stream>>>(pooledP, batch, proj_W, projP);
    ln_kernel<<<Bb, 512, 0, stream>>>(projP, proj_b, ln_gamma, ln_beta, out);
}

// Round 3
// 699.846 us; speedup vs baseline: 1.0317x; 1.0254x over previous
//
#include <hip/hip_runtime.h>
#include <hip/hip_bf16.h>
#include <hip/hip_fp8.h>
#include <math.h>

#define Nn 20000
#define Ee 320000
#define Dd 512
#define Hh 4
#define Cc 256
#define Ll 4
#define Bb 16
#define HC 1024               // H*C
#define ETOT (Ee + Nn)        // edges + self loops = 340000
#define NEG_SLOPE 0.2f
#define LN_EPS 1e-5f
#define NBLK ((Nn + 255) / 256)   // 79 scan blocks

typedef __attribute__((ext_vector_type(8))) __bf16 bf16x8;
typedef __attribute__((ext_vector_type(4))) __bf16 bf16x4;
typedef __attribute__((ext_vector_type(4))) float f32x4;
typedef __attribute__((ext_vector_type(2))) float f32x2;

// fp8 e4m3 (OCP) x4 decode — HW packed cvt if available
__device__ __forceinline__ f32x4 fp8x4_to_f32(unsigned int v) {
#if __has_builtin(__builtin_amdgcn_cvt_pk_f32_fp8)
    f32x2 lo = __builtin_amdgcn_cvt_pk_f32_fp8((int)v, false);
    f32x2 hi = __builtin_amdgcn_cvt_pk_f32_fp8((int)v, true);
    f32x4 r; r[0] = lo[0]; r[1] = lo[1]; r[2] = hi[0]; r[3] = hi[1];
    return r;
#else
    f32x4 r;
    #pragma unroll
    for (int i = 0; i < 4; ++i) {
        __hip_fp8_e4m3 q; q.__x = (v >> (8 * i)) & 0xff;
        r[i] = (float)q;
    }
    return r;
#endif
}

__device__ __forceinline__ unsigned char f32_to_fp8(float f) {
    return __hip_fp8_e4m3(f).__x;
}

// ---------------- CSR build ----------------

__device__ __forceinline__ void decode_edge(const int* ei, int e, int& s, int& d) {
    if (e < Ee) { s = ei[e]; d = ei[Ee + e]; }
    else        { s = e - Ee; d = e - Ee; }   // self loop
}

__global__ void count_deg_kernel(const int* __restrict__ ei, int* __restrict__ deg) {
    int e = blockIdx.x * blockDim.x + threadIdx.x;
    if (e >= ETOT) return;
    int s, d; decode_edge(ei, e, s, d);
    atomicAdd(&deg[d], 1);
}

__global__ void scan1_kernel(const int* __restrict__ deg, int* __restrict__ tmp,
                             int* __restrict__ bsum) {
    __shared__ int sd[256];
    int tid = threadIdx.x;
    int i = blockIdx.x * 256 + tid;
    sd[tid] = (i < Nn) ? deg[i] : 0;
    __syncthreads();
    for (int off = 1; off < 256; off <<= 1) {
        int t = (tid >= off) ? sd[tid - off] : 0;
        __syncthreads();
        sd[tid] += t;
        __syncthreads();
    }
    if (i < Nn) tmp[i] = sd[tid];
    if (tid == 255) bsum[blockIdx.x] = sd[255];
}

__global__ void scan2_kernel(int* __restrict__ bsum) {   // single block, NBLK<=256
    __shared__ int sd[256];
    int tid = threadIdx.x;
    sd[tid] = (tid < NBLK) ? bsum[tid] : 0;
    __syncthreads();
    for (int off = 1; off < 256; off <<= 1) {
        int t = (tid >= off) ? sd[tid - off] : 0;
        __syncthreads();
        sd[tid] += t;
        __syncthreads();
    }
    if (tid < NBLK) bsum[tid] = sd[tid];
}

__global__ void scan3_kernel(const int* __restrict__ tmp, const int* __restrict__ bsum,
                             const int* __restrict__ deg,
                             int* __restrict__ row_ptr, int* __restrict__ cursor) {
    int i = blockIdx.x * 256 + threadIdx.x;
    if (i >= Nn) return;
    int boff = (blockIdx.x == 0) ? 0 : bsum[blockIdx.x - 1];
    int incl = tmp[i] + boff;
    row_ptr[i + 1] = incl;
    cursor[i] = incl - deg[i];
    if (i == 0) row_ptr[0] = 0;
}

__global__ void scatter_kernel(const int* __restrict__ ei, int* __restrict__ cursor,
                               int* __restrict__ csr_src) {
    int e = blockIdx.x * blockDim.x + threadIdx.x;
    if (e >= ETOT) return;
    int s, d; decode_edge(ei, e, s, d);
    int pos = atomicAdd(&cursor[d], 1);
    csr_src[pos] = s;
}

// ---------------- casts ----------------

__global__ void cast_kernel(const float* __restrict__ in, __bf16* __restrict__ out, int n4) {
    int i = blockIdx.x * blockDim.x + threadIdx.x;
    if (i >= n4) return;
    f32x4 v = ((const f32x4*)in)[i];
    bf16x4 o;
    #pragma unroll
    for (int k = 0; k < 4; ++k) o[k] = (__bf16)v[k];
    ((bf16x4*)out)[i] = o;
}

// W[K][N] fp32 -> WT[N][K] bf16; grid.z selects matrix (stride K*N)
__global__ void transpose_cast_kernel(const float* __restrict__ W, __bf16* __restrict__ WT,
                                      int K, int N) {
    __shared__ float tile[32][33];
    W  += (size_t)blockIdx.z * K * N;
    WT += (size_t)blockIdx.z * K * N;
    int n0 = blockIdx.x * 32, k0 = blockIdx.y * 32;
    for (int i = threadIdx.y; i < 32; i += 8)
        tile[i][threadIdx.x] = W[(size_t)(k0 + i) * N + n0 + threadIdx.x];
    __syncthreads();
    for (int i = threadIdx.y; i < 32; i += 8)
        WT[(size_t)(n0 + i) * K + k0 + threadIdx.x] = (__bf16)tile[threadIdx.x][i];
}

// ---------------- MFMA GEMM + fused alpha epilogue ----------------
// C8[M,1024](fp8) = A[M,K](bf16) @ BT[1024,K]^T. XCD swizzle (r11: FETCH 162->34MB).
// r17: r14 geometry restored EXACTLY (128x128 tile, 256thr/4 waves, 2 blocks/CU —
// the cross-block overlap that actually delivered 26% util; r15/r16's 1-block/CU
// deep pipelines serialized ds_read vs MFMA behind shared barriers and regressed).
// Single change vs r14: K-tile DOUBLE BUFFER. Old: stage(kt)->sync(vmcnt0 drain!)
// ->compute->sync exposed full load latency each tile (m97's documented ~20%
// stall). New: stage(kt+1 -> buf^1) -> compute(buf) -> sync. The drain now lands
// a full compute-tile (~1200cy) after load issue => nearly free; one barrier per
// K-tile instead of two. LDS 32->64KB, still exactly 2 blocks/CU.
// Safety: buf[X^1] staged during tile kt was last ds_read in tile kt-1; those
// reads drained at tile kt-1's __syncthreads (lgkmcnt0). Epilogue unchanged:
// race-free part=(cblk&1)*2+(wave&1); alpha partials from in-register h.

__device__ __forceinline__ void async16(const __bf16* g, __bf16* l) {
    __builtin_amdgcn_global_load_lds((const __attribute__((address_space(1))) void*)g,
                                     (__attribute__((address_space(3))) void*)l,
                                     16, 0, 0);
}

__global__ __launch_bounds__(256) void mfma_gemm_kernel(
    const __bf16* __restrict__ A,   // [M][K]
    const __bf16* __restrict__ BT,  // [1024][K]
    unsigned char* __restrict__ C8, // [M][1024] fp8 e4m3 (agg gather payload)
    const float* __restrict__ att_s,  // [4][256] this layer
    const float* __restrict__ att_d,  // [4][256]
    float* __restrict__ aprt_s,     // [4][M][4] partials (race-free)
    float* __restrict__ aprt_d,     // [4][M][4]
    int M, int K)
{
    int lin = blockIdx.y * 8 + blockIdx.x;          // grid (8, 160) -> 1280 ids
    int rblk = (lin >> 6) * 8 + (lin & 7);
    int cblk = (lin >> 3) & 7;
    int rowBase = rblk * 128, colBase = cblk * 128;
    if (rowBase >= M) return;

    __shared__ __bf16 As[2][2][128 * 32];   // [tile-dbuf][p-half] 32KB
    __shared__ __bf16 Bs[2][2][128 * 32];   // 32KB (64KB total -> 2 blocks/CU)
    int tid = threadIdx.x;
    int wave = tid >> 6, lane = tid & 63;
    int m16 = lane & 15, quad = lane >> 4;
    int waveRow = (wave >> 1) * 64, waveCol = (wave & 1) * 64;

    f32x4 acc[4][4] = {};

    int srow = wave * 32 + (lane >> 2);          // staging row, +16 for second half
    int gch0 = (lane & 3) ^ ((srow >> 1) & 3);
    int gch1 = (lane & 3) ^ (((srow + 16) >> 1) & 3);
    int gr0 = rowBase + srow;       if (gr0 >= M) gr0 = M - 1;
    int gr1 = rowBase + srow + 16;  if (gr1 >= M) gr1 = M - 1;
    int ldsOff = srow * 32 + (lane & 3) * 8;

    // stage K-tile kt (both 32-halves) into buffer X
    auto stage = [&](int kt, int X) {
        #pragma unroll
        for (int p = 0; p < 2; ++p) {
            int kp = kt * 64 + p * 32;
            async16(A + (size_t)gr0 * K + kp + gch0 * 8, &As[X][p][ldsOff]);
            async16(A + (size_t)gr1 * K + kp + gch1 * 8, &As[X][p][ldsOff + 16 * 32]);
            async16(BT + (size_t)(colBase + srow) * K + kp + gch0 * 8, &Bs[X][p][ldsOff]);
            async16(BT + (size_t)(colBase + srow + 16) * K + kp + gch1 * 8, &Bs[X][p][ldsOff + 16 * 32]);
        }
    };

    stage(0, 0);
    __syncthreads();   // drains tile-0 loads (cold start, unavoidable once)

    int NT = K >> 6;
    for (int kt = 0; kt < NT; ++kt) {
        int X = kt & 1;
        if (kt + 1 < NT) stage(kt + 1, X ^ 1);   // issue EARLY; drained at tile-end sync
        #pragma unroll
        for (int p = 0; p < 2; ++p) {
            bf16x8 af[4], bfr[4];
            #pragma unroll
            for (int i = 0; i < 4; ++i) {
                int row = waveRow + i * 16 + m16;
                af[i] = *(const bf16x8*)&As[X][p][row * 32 + (quad ^ ((row >> 1) & 3)) * 8];
                int col = waveCol + i * 16 + m16;
                bfr[i] = *(const bf16x8*)&Bs[X][p][col * 32 + (quad ^ ((col >> 1) & 3)) * 8];
            }
            #pragma unroll
            for (int i = 0; i < 4; ++i)
                #pragma unroll
                for (int j = 0; j < 4; ++j)
                    acc[i][j] = __builtin_amdgcn_mfma_f32_16x16x32_bf16(af[i], bfr[j], acc[i][j], 0, 0, 0);
        }
        __syncthreads();   // publish buf[X^1] (vmcnt0) + protect buf[X] (lgkm0)
    }

    // att weights for this wave's 64-col span (single head: span never crosses 256)
    int cbase = colBase + waveCol;
    int head = cbase >> 8;
    int part = (cblk & 1) * 2 + (wave & 1);
    float as4[4], ad4[4];
    #pragma unroll
    for (int j = 0; j < 4; ++j) {
        int off = (cbase + j * 16 + m16) & 255;
        as4[j] = att_s[head * 256 + off];
        ad4[j] = att_d[head * 256 + off];
    }

    // fp8 stores (C/D layout: col=lane&15, row=quad*4+reg) + alpha partials
    #pragma unroll
    for (int i = 0; i < 4; ++i) {
        int r0 = rowBase + waveRow + i * 16 + quad * 4;
        #pragma unroll
        for (int r = 0; r < 4; ++r) {
            int row = r0 + r;
            float ps = 0.f, pd = 0.f;
            #pragma unroll
            for (int j = 0; j < 4; ++j) {
                float h = acc[i][j][r];
                ps += h * as4[j];
                pd += h * ad4[j];
                if (row < M)
                    C8[(size_t)row * HC + colBase + waveCol + j * 16 + m16] = f32_to_fp8(h);
            }
            #pragma unroll
            for (int off = 1; off < 16; off <<= 1) {
                ps += __shfl_xor(ps, off);
                pd += __shfl_xor(pd, off);
            }
            if (m16 == 0 && row < M) {
                aprt_s[((size_t)part * M + row) * 4 + head] = ps;
                aprt_d[((size_t)part * M + row) * 4 + head] = pd;
            }
        }
    }
}

// ---------------- alpha partial reduce: asrc/adst[n] = sum over 4 parts ----------------

__global__ void alpha_sum_kernel(const float* __restrict__ aprt_s,
                                 const float* __restrict__ aprt_d,
                                 float* __restrict__ asrc, float* __restrict__ adst) {
    int n = blockIdx.x * 256 + threadIdx.x;
    if (n >= Nn) return;
    f32x4 s = {0.f, 0.f, 0.f, 0.f}, d = {0.f, 0.f, 0.f, 0.f};
    #pragma unroll
    for (int p = 0; p < 4; ++p) {
        f32x4 vs = ((const f32x4*)aprt_s)[(size_t)p * Nn + n];
        f32x4 vd = ((const f32x4*)aprt_d)[(size_t)p * Nn + n];
        #pragma unroll
        for (int k = 0; k < 4; ++k) { s[k] += vs[k]; d[k] += vd[k]; }
    }
    ((f32x4*)asrc)[n] = s;
    ((f32x4*)adst)[n] = d;
}

// ---------------- edge-weight precompute (head-major output) ----------------

__global__ __launch_bounds__(256) void ew_kernel(const float* __restrict__ asrc,
                                                 const float* __restrict__ adst,
                                                 const int* __restrict__ row_ptr,
                                                 const int* __restrict__ csr_src,
                                                 float* __restrict__ ewT,
                                                 float* __restrict__ dinv) {
    int w = threadIdx.x >> 6, lane = threadIdx.x & 63;
    int n = blockIdx.x * 4 + w;
    if (n >= Nn) return;
    int start = row_ptr[n], end = row_ptr[n + 1];
    f32x4 ad = ((const f32x4*)adst)[n];
    f32x4 d = {0.f, 0.f, 0.f, 0.f};
    for (int e = start + lane; e < end; e += 64) {
        int s = csr_src[e];
        f32x4 as = ((const f32x4*)asrc)[s];
        #pragma unroll
        for (int k = 0; k < 4; ++k) {
            float z = as[k] + ad[k];
            z = (z > 0.f) ? z : NEG_SLOPE * z;
            float ex = __expf(z);
            ewT[(size_t)k * ETOT + e] = ex;
            d[k] += ex;
        }
    }
    #pragma unroll
    for (int off = 32; off > 0; off >>= 1) {
        #pragma unroll
        for (int k = 0; k < 4; ++k) d[k] += __shfl_down(d[k], off);
    }
    if (lane == 0) {
        f32x4 iv;
        #pragma unroll
        for (int k = 0; k < 4; ++k) iv[k] = 1.f / (d[k] + 1e-16f);
        ((f32x4*)dinv)[n] = iv;
    }
}

// ---------------- sliced aggregation (r11-proven: fp8, 8 ch/thread, 2-wide) ----------------
// grid (8, 1250): slice -> XCD affinity; per-XCD footprint 2.5MB (96% L2 hit, r10).
// Block = 16 node-slots x 16 ch-threads; each thread serially walks ITS node's
// edges for 8 fp8 channels (8B loads). No fused epilogue (r12/r13: latency-hiding loss).

__global__ __launch_bounds__(256) void agg_slice_kernel(
    const unsigned char* __restrict__ h8,
    const float* __restrict__ ewT,
    const float* __restrict__ dinv,
    const int* __restrict__ row_ptr,
    const int* __restrict__ csr_src,
    const float* __restrict__ bias_l,
    __bf16* __restrict__ outb)
{
    int slice = blockIdx.x;              // 0..7
    int head = slice >> 1;
    int tid = threadIdx.x;
    int nslot = tid >> 4;                // 0..15
    int ch = tid & 15;                   // 8B fp8 group within 128B slice
    int n = blockIdx.y * 16 + nslot;

    __shared__ int   csr_sh[512];
    __shared__ float ew_sh[512];
    __shared__ int   rp_sh[17];

    if (tid < 17) rp_sh[tid] = row_ptr[blockIdx.y * 16 + tid];
    __syncthreads();
    int blk_lo = rp_sh[0], blk_hi = rp_sh[16];
    int start = rp_sh[nslot], end = rp_sh[nslot + 1];

    const unsigned char* hs = h8 + slice * 128 + ch * 8;
    const float* ewh = ewT + (size_t)head * ETOT;
    float acc[8] = {};

    for (int c0 = blk_lo; c0 < blk_hi; c0 += 512) {
        int c1 = min(c0 + 512, blk_hi);
        int cnt = c1 - c0;
        for (int i = tid; i < cnt; i += 256) {     // coalesced stage
            csr_sh[i] = csr_src[c0 + i];
            ew_sh[i]  = ewh[c0 + i];
        }
        __syncthreads();
        int lo = max(start, c0), hi = min(end, c1);
        int e = lo;
        for (; e + 1 < hi; e += 2) {
            int s0 = csr_sh[e - c0], s1 = csr_sh[e + 1 - c0];
            float w0 = ew_sh[e - c0], w1 = ew_sh[e + 1 - c0];
            uint2 u0 = *(const uint2*)(hs + (size_t)s0 * HC);
            uint2 u1 = *(const uint2*)(hs + (size_t)s1 * HC);
            f32x4 a0 = fp8x4_to_f32(u0.x), b0 = fp8x4_to_f32(u0.y);
            f32x4 a1 = fp8x4_to_f32(u1.x), b1 = fp8x4_to_f32(u1.y);
            #pragma unroll
            for (int k = 0; k < 4; ++k) {
                acc[k]     += w0 * a0[k];
                acc[k + 4] += w0 * b0[k];
                acc[k]     += w1 * a1[k];
                acc[k + 4] += w1 * b1[k];
            }
        }
        if (e < hi) {
            int s0 = csr_sh[e - c0];
            float w0 = ew_sh[e - c0];
            uint2 u0 = *(const uint2*)(hs + (size_t)s0 * HC);
            f32x4 a0 = fp8x4_to_f32(u0.x), b0 = fp8x4_to_f32(u0.y);
            #pragma unroll
            for (int k = 0; k < 4; ++k) {
                acc[k]     += w0 * a0[k];
                acc[k + 4] += w0 * b0[k];
            }
        }
        __syncthreads();
    }

    float inv = dinv[n * 4 + head];
    bf16x8 o;
    #pragma unroll
    for (int k = 0; k < 8; ++k)
        o[k] = (__bf16)fmaxf(acc[k] * inv + bias_l[slice * 128 + ch * 8 + k], 0.f);
    *(bf16x8*)(outb + (size_t)n * HC + slice * 128 + ch * 8) = o;
}

// ---------------- global mean pool (race-free partials) ----------------

__device__ __forceinline__ int lower_bound_batch(const int* __restrict__ batch, int val) {
    int lo = 0, hi = Nn;
    while (lo < hi) { int mid = (lo + hi) >> 1; if (batch[mid] < val) lo = mid + 1; else hi = mid; }
    return lo;
}

__global__ void pool_kernel(const __bf16* __restrict__ h2b, const int* __restrict__ batch,
                            float* __restrict__ pooledP) {
    int b = blockIdx.x, part = blockIdx.y;   // grid (B, 8)
    int tid = threadIdx.x;
    int start = lower_bound_batch(batch, b);
    int end   = lower_bound_batch(batch, b + 1);
    int len = end - start;
    int chunk = (len + 7) / 8;
    int s0 = start + part * chunk;
    int s1 = min(s0 + chunk, end);
    float acc[4] = {0.f, 0.f, 0.f, 0.f};
    for (int n = s0; n < s1; ++n) {
        bf16x4 v = ((const bf16x4*)(h2b + (size_t)n * HC))[tid];
        #pragma unroll
        for (int k = 0; k < 4; ++k) acc[k] += (float)v[k];
    }
    #pragma unroll
    for (int k = 0; k < 4; ++k)
        pooledP[((size_t)part * Bb + b) * HC + tid * 4 + k] = acc[k];
}

// ---------------- projection (k-split, race-free partials) + layernorm ----------------

__global__ __launch_bounds__(512) void proj_partial_kernel(const float* __restrict__ pooledP,
                                                           const int* __restrict__ batch,
                                                           const float* __restrict__ projW,
                                                           float* __restrict__ projP) {
    int b = blockIdx.x, part = blockIdx.y;   // grid (16, 8)
    int d = threadIdx.x;                     // 512
    __shared__ float psum[HC];
    int start = lower_bound_batch(batch, b);
    int end   = lower_bound_batch(batch, b + 1);
    float inv = 1.0f / fmaxf((float)(end - start), 1.0f);
    for (int k = d; k < HC; k += 512) {
        float s = 0.f;
        #pragma unroll
        for (int p = 0; p < 8; ++p) s += pooledP[((size_t)p * Bb + b) * HC + k];
        psum[k] = s * inv;
    }
    __syncthreads();
    float acc = 0.f;
    int k0 = part * 128;
    for (int k = k0; k < k0 + 128; ++k)
        acc += psum[k] * projW[(size_t)k * Dd + d];
    projP[((size_t)part * Bb + b) * Dd + d] = acc;
}

__global__ __launch_bounds__(512) void ln_kernel(const float* __restrict__ projP,
                                                 const float* __restrict__ projb,
                                                 const float* __restrict__ gamma,
                                                 const float* __restrict__ beta,
                                                 float* __restrict__ out) {
    int b = blockIdx.x;
    int d = threadIdx.x;
    __shared__ float red[512];
    float o = projb[d];
    #pragma unroll
    for (int p = 0; p < 8; ++p) o += projP[((size_t)p * Bb + b) * Dd + d];
    red[d] = o;
    __syncthreads();
    for (int off = 256; off > 0; off >>= 1) {
        if (d < off) red[d] += red[d + off];
        __syncthreads();
    }
    float mu = red[0] / (float)Dd;
    __syncthreads();
    float df = o - mu;
    red[d] = df * df;
    __syncthreads();
    for (int off = 256; off > 0; off >>= 1) {
        if (d < off) red[d] += red[d + off];
        __syncthreads();
    }
    float var = red[0] / (float)Dd;
    out[b * Dd + d] = df / sqrtf(var + LN_EPS) * gamma[d] + beta[d];
}

// ---------------- launch ----------------

extern "C" void kernel_launch(void* const* d_in, const int* in_sizes, int n_in,
                              void* d_out, int out_size, void* d_ws, size_t ws_size,
                              hipStream_t stream) {
    const float* x         = (const float*)d_in[0];
    const int*   ei        = (const int*)d_in[1];
    const int*   batch     = (const int*)d_in[2];
    const float* W0        = (const float*)d_in[3];
    const float* W_rest    = (const float*)d_in[4];
    const float* att_src   = (const float*)d_in[5];
    const float* att_dst   = (const float*)d_in[6];
    const float* conv_bias = (const float*)d_in[7];
    const float* proj_W    = (const float*)d_in[8];
    const float* proj_b    = (const float*)d_in[9];
    const float* ln_gamma  = (const float*)d_in[10];
    const float* ln_beta   = (const float*)d_in[11];
    float* out = (float*)d_out;

    char* ws = (char*)d_ws;
    size_t off = 0;
    auto alloc = [&](size_t bytes) {
        void* p = ws + off;
        off = (off + bytes + 255) & ~(size_t)255;
        return p;
    };
    unsigned char* h8 = (unsigned char*)alloc((size_t)Nn * HC);   // GEMM out (fp8, agg payload)
    __bf16* h2b     = (__bf16*)alloc((size_t)Nn * HC * 2);        // layer out (bf16)
    __bf16* xb      = (__bf16*)alloc((size_t)Nn * Dd * 2);
    __bf16* W0T     = (__bf16*)alloc((size_t)HC * Dd * 2);
    __bf16* WrT     = (__bf16*)alloc((size_t)3 * HC * HC * 2);
    float*  aprt_s  = (float*)alloc((size_t)4 * Nn * Hh * 4);     // alpha partials
    float*  aprt_d  = (float*)alloc((size_t)4 * Nn * Hh * 4);
    float*  asrc    = (float*)alloc((size_t)Nn * Hh * 4);
    float*  adst    = (float*)alloc((size_t)Nn * Hh * 4);
    float*  ewT     = (float*)alloc((size_t)Hh * ETOT * 4);       // head-major
    float*  dinv    = (float*)alloc((size_t)Nn * Hh * 4);
    int*    deg     = (int*)alloc((size_t)Nn * 4);
    int*    tmp     = (int*)alloc((size_t)Nn * 4);
    int*    bsum    = (int*)alloc((size_t)256 * 4);
    int*    row_ptr = (int*)alloc((size_t)(Nn + 1) * 4);
    int*    cursor  = (int*)alloc((size_t)Nn * 4);
    int*    csr_src = (int*)alloc((size_t)ETOT * 4);
    float*  pooledP = (float*)alloc((size_t)8 * Bb * HC * 4);
    float*  projP   = (float*)alloc((size_t)8 * Bb * Dd * 4);
    (void)ws_size; (void)in_sizes; (void)n_in; (void)out_size;

    // ---- build CSR by destination ----
    hipMemsetAsync(deg, 0, (size_t)Nn * 4, stream);
    count_deg_kernel<<<(ETOT + 255) / 256, 256, 0, stream>>>(ei, deg);
    scan1_kernel<<<NBLK, 256, 0, stream>>>(deg, tmp, bsum);
    scan2_kernel<<<1, 256, 0, stream>>>(bsum);
    scan3_kernel<<<NBLK, 256, 0, stream>>>(tmp, bsum, deg, row_ptr, cursor);
    scatter_kernel<<<(ETOT + 255) / 256, 256, 0, stream>>>(ei, cursor, csr_src);

    // ---- bf16 casts / weight transposes ----
    cast_kernel<<<(Nn * Dd / 4 + 255) / 256, 256, 0, stream>>>(x, xb, Nn * Dd / 4);
    transpose_cast_kernel<<<dim3(HC / 32, Dd / 32, 1), dim3(32, 8), 0, stream>>>(W0, W0T, Dd, HC);
    transpose_cast_kernel<<<dim3(HC / 32, HC / 32, 3), dim3(32, 8), 0, stream>>>(W_rest, WrT, HC, HC);

    // ---- GAT layers ----
    dim3 gemm_grid(8, 160);   // 1280 swizzled ids -> (157 row-blocks, 8 col-blocks)
    for (int l = 0; l < Ll; ++l) {
        const __bf16* Afeat = (l == 0) ? xb : h2b;
        int K = (l == 0) ? Dd : HC;
        const __bf16* BT = (l == 0) ? W0T : (WrT + (size_t)(l - 1) * HC * HC);
        mfma_gemm_kernel<<<gemm_grid, 256, 0, stream>>>(
            Afeat, BT, h8, att_src + l * HC, att_dst + l * HC, aprt_s, aprt_d, Nn, K);
        alpha_sum_kernel<<<NBLK, 256, 0, stream>>>(aprt_s, aprt_d, asrc, adst);
        ew_kernel<<<(Nn + 3) / 4, 256, 0, stream>>>(asrc, adst, row_ptr, csr_src, ewT, dinv);
        agg_slice_kernel<<<dim3(8, Nn / 16), 256, 0, stream>>>(
            h8, ewT, dinv, row_ptr, csr_src, conv_bias + l * HC, h2b);
    }

    // ---- pool + proj + layernorm (all race-free partials, no memsets) ----
    pool_kernel<<<dim3(Bb, 8), 256, 0, stream>>>(h2b, batch, pooledP);
    proj_partial_kernel<<<dim3(Bb, 8), 512, 0, stream>>>(pooledP, batch, proj_W, projP);
    ln_kernel<<<Bb, 512, 0, stream>>>(projP, proj_b, ln_gamma, ln_beta, out);
}

// Round 4
// 654.960 us; speedup vs baseline: 1.1024x; 1.0685x over previous
//
#include <hip/hip_runtime.h>
#include <hip/hip_bf16.h>
#include <hip/hip_fp8.h>
#include <math.h>

#define Nn 20000
#define Ee 320000
#define Dd 512
#define Hh 4
#define Cc 256
#define Ll 4
#define Bb 16
#define HC 1024               // H*C
#define ETOT (Ee + Nn)        // edges + self loops = 340000
#define NEG_SLOPE 0.2f
#define LN_EPS 1e-5f
#define NBLK ((Nn + 255) / 256)   // 79 scan blocks

typedef __attribute__((ext_vector_type(8))) __bf16 bf16x8;
typedef __attribute__((ext_vector_type(4))) __bf16 bf16x4;
typedef __attribute__((ext_vector_type(4))) float f32x4;
typedef __attribute__((ext_vector_type(2))) float f32x2;

// fp8 e4m3 (OCP) x4 decode — HW packed cvt if available
__device__ __forceinline__ f32x4 fp8x4_to_f32(unsigned int v) {
#if __has_builtin(__builtin_amdgcn_cvt_pk_f32_fp8)
    f32x2 lo = __builtin_amdgcn_cvt_pk_f32_fp8((int)v, false);
    f32x2 hi = __builtin_amdgcn_cvt_pk_f32_fp8((int)v, true);
    f32x4 r; r[0] = lo[0]; r[1] = lo[1]; r[2] = hi[0]; r[3] = hi[1];
    return r;
#else
    f32x4 r;
    #pragma unroll
    for (int i = 0; i < 4; ++i) {
        __hip_fp8_e4m3 q; q.__x = (v >> (8 * i)) & 0xff;
        r[i] = (float)q;
    }
    return r;
#endif
}

__device__ __forceinline__ unsigned char f32_to_fp8(float f) {
    return __hip_fp8_e4m3(f).__x;
}

// ---------------- CSR build ----------------

__device__ __forceinline__ void decode_edge(const int* ei, int e, int& s, int& d) {
    if (e < Ee) { s = ei[e]; d = ei[Ee + e]; }
    else        { s = e - Ee; d = e - Ee; }   // self loop
}

__global__ void count_deg_kernel(const int* __restrict__ ei, int* __restrict__ deg) {
    int e = blockIdx.x * blockDim.x + threadIdx.x;
    if (e >= ETOT) return;
    int s, d; decode_edge(ei, e, s, d);
    atomicAdd(&deg[d], 1);
}

__global__ void scan1_kernel(const int* __restrict__ deg, int* __restrict__ tmp,
                             int* __restrict__ bsum) {
    __shared__ int sd[256];
    int tid = threadIdx.x;
    int i = blockIdx.x * 256 + tid;
    sd[tid] = (i < Nn) ? deg[i] : 0;
    __syncthreads();
    for (int off = 1; off < 256; off <<= 1) {
        int t = (tid >= off) ? sd[tid - off] : 0;
        __syncthreads();
        sd[tid] += t;
        __syncthreads();
    }
    if (i < Nn) tmp[i] = sd[tid];
    if (tid == 255) bsum[blockIdx.x] = sd[255];
}

__global__ void scan2_kernel(int* __restrict__ bsum) {   // single block, NBLK<=256
    __shared__ int sd[256];
    int tid = threadIdx.x;
    sd[tid] = (tid < NBLK) ? bsum[tid] : 0;
    __syncthreads();
    for (int off = 1; off < 256; off <<= 1) {
        int t = (tid >= off) ? sd[tid - off] : 0;
        __syncthreads();
        sd[tid] += t;
        __syncthreads();
    }
    if (tid < NBLK) bsum[tid] = sd[tid];
}

__global__ void scan3_kernel(const int* __restrict__ tmp, const int* __restrict__ bsum,
                             const int* __restrict__ deg,
                             int* __restrict__ row_ptr, int* __restrict__ cursor) {
    int i = blockIdx.x * 256 + threadIdx.x;
    if (i >= Nn) return;
    int boff = (blockIdx.x == 0) ? 0 : bsum[blockIdx.x - 1];
    int incl = tmp[i] + boff;
    row_ptr[i + 1] = incl;
    cursor[i] = incl - deg[i];
    if (i == 0) row_ptr[0] = 0;
}

__global__ void scatter_kernel(const int* __restrict__ ei, int* __restrict__ cursor,
                               int* __restrict__ csr_src) {
    int e = blockIdx.x * blockDim.x + threadIdx.x;
    if (e >= ETOT) return;
    int s, d; decode_edge(ei, e, s, d);
    int pos = atomicAdd(&cursor[d], 1);
    csr_src[pos] = s;
}

// ---------------- casts ----------------

__global__ void cast_kernel(const float* __restrict__ in, __bf16* __restrict__ out, int n4) {
    int i = blockIdx.x * blockDim.x + threadIdx.x;
    if (i >= n4) return;
    f32x4 v = ((const f32x4*)in)[i];
    bf16x4 o;
    #pragma unroll
    for (int k = 0; k < 4; ++k) o[k] = (__bf16)v[k];
    ((bf16x4*)out)[i] = o;
}

// W[K][N] fp32 -> WT[N][K] bf16; grid.z selects matrix (stride K*N)
__global__ void transpose_cast_kernel(const float* __restrict__ W, __bf16* __restrict__ WT,
                                      int K, int N) {
    __shared__ float tile[32][33];
    W  += (size_t)blockIdx.z * K * N;
    WT += (size_t)blockIdx.z * K * N;
    int n0 = blockIdx.x * 32, k0 = blockIdx.y * 32;
    for (int i = threadIdx.y; i < 32; i += 8)
        tile[i][threadIdx.x] = W[(size_t)(k0 + i) * N + n0 + threadIdx.x];
    __syncthreads();
    for (int i = threadIdx.y; i < 32; i += 8)
        WT[(size_t)(n0 + i) * K + k0 + threadIdx.x] = (__bf16)tile[threadIdx.x][i];
}

// ---------------- MFMA GEMM + fused alpha epilogue (r0 VERBATIM — proven 65us) ----------
// C8[M,1024](fp8) = A[M,K](bf16) @ BT[1024,K]^T. XCD swizzle (r11: FETCH 162->34MB).
// r18 note: r15/r16/r17 all tried intra-block pipelining (counted vmcnt, deep
// buffers, issue-early dbuf) and ALL regressed (98/83/77us vs 65us): every scheme
// grew LDS and traded away co-resident blocks; inter-block overlap (m114) beats
// intra-block pipelining here. This 32KB-LDS stage->sync->compute->sync structure
// at 2+ blocks/CU is the empirical local optimum — do not touch without new
// counter evidence.
// Epilogue computes alpha partials ps/pd from IN-REGISTER h (zero extra traffic).
// Race-free: part=(cblk&1)*2+(wave&1) — for fixed (row,head) the 4 writers
// (cblk in {2h,2h+1} x wave&1) get distinct parts. No atomics, no pre-zeroing.

__device__ __forceinline__ void async16(const __bf16* g, __bf16* l) {
    __builtin_amdgcn_global_load_lds((const __attribute__((address_space(1))) void*)g,
                                     (__attribute__((address_space(3))) void*)l,
                                     16, 0, 0);
}

__global__ __launch_bounds__(256) void mfma_gemm_kernel(
    const __bf16* __restrict__ A,   // [M][K]
    const __bf16* __restrict__ BT,  // [1024][K]
    unsigned char* __restrict__ C8, // [M][1024] fp8 e4m3 (agg gather payload)
    const float* __restrict__ att_s,  // [4][256] this layer
    const float* __restrict__ att_d,  // [4][256]
    float* __restrict__ aprt_s,     // [4][M][4] partials (race-free)
    float* __restrict__ aprt_d,     // [4][M][4]
    int M, int K)
{
    int lin = blockIdx.y * 8 + blockIdx.x;          // grid (8, 160) -> 1280 ids
    int rblk = (lin >> 6) * 8 + (lin & 7);
    int cblk = (lin >> 3) & 7;
    int rowBase = rblk * 128, colBase = cblk * 128;
    if (rowBase >= M) return;

    __shared__ __bf16 As[2][128 * 32];
    __shared__ __bf16 Bs[2][128 * 32];
    int tid = threadIdx.x;
    int wave = tid >> 6, lane = tid & 63;
    int m16 = lane & 15, quad = lane >> 4;
    int waveRow = (wave >> 1) * 64, waveCol = (wave & 1) * 64;

    f32x4 acc[4][4] = {};

    int srow = wave * 32 + (lane >> 2);          // staging row, +16 for second half
    int gch0 = (lane & 3) ^ ((srow >> 1) & 3);
    int gch1 = (lane & 3) ^ (((srow + 16) >> 1) & 3);
    int gr0 = rowBase + srow;       if (gr0 >= M) gr0 = M - 1;
    int gr1 = rowBase + srow + 16;  if (gr1 >= M) gr1 = M - 1;
    int ldsOff = srow * 32 + (lane & 3) * 8;

    for (int k0 = 0; k0 < K; k0 += 64) {
        #pragma unroll
        for (int p = 0; p < 2; ++p) {
            int kp = k0 + p * 32;
            async16(A + (size_t)gr0 * K + kp + gch0 * 8, &As[p][ldsOff]);
            async16(A + (size_t)gr1 * K + kp + gch1 * 8, &As[p][ldsOff + 16 * 32]);
            async16(BT + (size_t)(colBase + srow) * K + kp + gch0 * 8, &Bs[p][ldsOff]);
            async16(BT + (size_t)(colBase + srow + 16) * K + kp + gch1 * 8, &Bs[p][ldsOff + 16 * 32]);
        }
        __syncthreads();
        #pragma unroll
        for (int p = 0; p < 2; ++p) {
            bf16x8 af[4], bfr[4];
            #pragma unroll
            for (int i = 0; i < 4; ++i) {
                int row = waveRow + i * 16 + m16;
                af[i] = *(const bf16x8*)&As[p][row * 32 + (quad ^ ((row >> 1) & 3)) * 8];
                int col = waveCol + i * 16 + m16;
                bfr[i] = *(const bf16x8*)&Bs[p][col * 32 + (quad ^ ((col >> 1) & 3)) * 8];
            }
            #pragma unroll
            for (int i = 0; i < 4; ++i)
                #pragma unroll
                for (int j = 0; j < 4; ++j)
                    acc[i][j] = __builtin_amdgcn_mfma_f32_16x16x32_bf16(af[i], bfr[j], acc[i][j], 0, 0, 0);
        }
        __syncthreads();
    }

    // att weights for this wave's 64-col span (single head: span never crosses 256)
    int cbase = colBase + waveCol;
    int head = cbase >> 8;
    int part = (cblk & 1) * 2 + (wave & 1);
    float as4[4], ad4[4];
    #pragma unroll
    for (int j = 0; j < 4; ++j) {
        int off = (cbase + j * 16 + m16) & 255;
        as4[j] = att_s[head * 256 + off];
        ad4[j] = att_d[head * 256 + off];
    }

    // fp8 stores (C/D layout: col=lane&15, row=quad*4+reg) + alpha partials
    #pragma unroll
    for (int i = 0; i < 4; ++i) {
        int r0 = rowBase + waveRow + i * 16 + quad * 4;
        #pragma unroll
        for (int r = 0; r < 4; ++r) {
            int row = r0 + r;
            float ps = 0.f, pd = 0.f;
            #pragma unroll
            for (int j = 0; j < 4; ++j) {
                float h = acc[i][j][r];
                ps += h * as4[j];
                pd += h * ad4[j];
                if (row < M)
                    C8[(size_t)row * HC + colBase + waveCol + j * 16 + m16] = f32_to_fp8(h);
            }
            #pragma unroll
            for (int off = 1; off < 16; off <<= 1) {
                ps += __shfl_xor(ps, off);
                pd += __shfl_xor(pd, off);
            }
            if (m16 == 0 && row < M) {
                aprt_s[((size_t)part * M + row) * 4 + head] = ps;
                aprt_d[((size_t)part * M + row) * 4 + head] = pd;
            }
        }
    }
}

// ---------------- alpha partial reduce: asrc/adst[n] = sum over 4 parts ----------------

__global__ void alpha_sum_kernel(const float* __restrict__ aprt_s,
                                 const float* __restrict__ aprt_d,
                                 float* __restrict__ asrc, float* __restrict__ adst) {
    int n = blockIdx.x * 256 + threadIdx.x;
    if (n >= Nn) return;
    f32x4 s = {0.f, 0.f, 0.f, 0.f}, d = {0.f, 0.f, 0.f, 0.f};
    #pragma unroll
    for (int p = 0; p < 4; ++p) {
        f32x4 vs = ((const f32x4*)aprt_s)[(size_t)p * Nn + n];
        f32x4 vd = ((const f32x4*)aprt_d)[(size_t)p * Nn + n];
        #pragma unroll
        for (int k = 0; k < 4; ++k) { s[k] += vs[k]; d[k] += vd[k]; }
    }
    ((f32x4*)asrc)[n] = s;
    ((f32x4*)adst)[n] = d;
}

// ---------------- edge-weight precompute (head-major output) ----------------

__global__ __launch_bounds__(256) void ew_kernel(const float* __restrict__ asrc,
                                                 const float* __restrict__ adst,
                                                 const int* __restrict__ row_ptr,
                                                 const int* __restrict__ csr_src,
                                                 float* __restrict__ ewT,
                                                 float* __restrict__ dinv) {
    int w = threadIdx.x >> 6, lane = threadIdx.x & 63;
    int n = blockIdx.x * 4 + w;
    if (n >= Nn) return;
    int start = row_ptr[n], end = row_ptr[n + 1];
    f32x4 ad = ((const f32x4*)adst)[n];
    f32x4 d = {0.f, 0.f, 0.f, 0.f};
    for (int e = start + lane; e < end; e += 64) {
        int s = csr_src[e];
        f32x4 as = ((const f32x4*)asrc)[s];
        #pragma unroll
        for (int k = 0; k < 4; ++k) {
            float z = as[k] + ad[k];
            z = (z > 0.f) ? z : NEG_SLOPE * z;
            float ex = __expf(z);
            ewT[(size_t)k * ETOT + e] = ex;
            d[k] += ex;
        }
    }
    #pragma unroll
    for (int off = 32; off > 0; off >>= 1) {
        #pragma unroll
        for (int k = 0; k < 4; ++k) d[k] += __shfl_down(d[k], off);
    }
    if (lane == 0) {
        f32x4 iv;
        #pragma unroll
        for (int k = 0; k < 4; ++k) iv[k] = 1.f / (d[k] + 1e-16f);
        ((f32x4*)dinv)[n] = iv;
    }
}

// ---------------- sliced aggregation (r11-proven: fp8, 8 ch/thread) ----------------
// grid (8, 1250): slice -> XCD affinity; per-XCD footprint 2.5MB (96% L2 hit, r10).
// Block = 16 node-slots x 16 ch-threads; each thread serially walks ITS node's
// edges for 8 fp8 channels (8B loads). r18: edge loop widened 2->4 (4 outstanding
// gathers/thread — at 14% of L2 BW the loop is latency/MLP-bound, not BW-bound).
// Adds stay in ascending-e order into the same accumulators => bitwise-identical.

__global__ __launch_bounds__(256) void agg_slice_kernel(
    const unsigned char* __restrict__ h8,
    const float* __restrict__ ewT,
    const float* __restrict__ dinv,
    const int* __restrict__ row_ptr,
    const int* __restrict__ csr_src,
    const float* __restrict__ bias_l,
    __bf16* __restrict__ outb)
{
    int slice = blockIdx.x;              // 0..7
    int head = slice >> 1;
    int tid = threadIdx.x;
    int nslot = tid >> 4;                // 0..15
    int ch = tid & 15;                   // 8B fp8 group within 128B slice
    int n = blockIdx.y * 16 + nslot;

    __shared__ int   csr_sh[512];
    __shared__ float ew_sh[512];
    __shared__ int   rp_sh[17];

    if (tid < 17) rp_sh[tid] = row_ptr[blockIdx.y * 16 + tid];
    __syncthreads();
    int blk_lo = rp_sh[0], blk_hi = rp_sh[16];
    int start = rp_sh[nslot], end = rp_sh[nslot + 1];

    const unsigned char* hs = h8 + slice * 128 + ch * 8;
    const float* ewh = ewT + (size_t)head * ETOT;
    float acc[8] = {};

    for (int c0 = blk_lo; c0 < blk_hi; c0 += 512) {
        int c1 = min(c0 + 512, blk_hi);
        int cnt = c1 - c0;
        for (int i = tid; i < cnt; i += 256) {     // coalesced stage
            csr_sh[i] = csr_src[c0 + i];
            ew_sh[i]  = ewh[c0 + i];
        }
        __syncthreads();
        int lo = max(start, c0), hi = min(end, c1);
        int e = lo;
        for (; e + 3 < hi; e += 4) {
            int s0 = csr_sh[e - c0],     s1 = csr_sh[e + 1 - c0];
            int s2 = csr_sh[e + 2 - c0], s3 = csr_sh[e + 3 - c0];
            float w0 = ew_sh[e - c0],     w1 = ew_sh[e + 1 - c0];
            float w2 = ew_sh[e + 2 - c0], w3 = ew_sh[e + 3 - c0];
            uint2 u0 = *(const uint2*)(hs + (size_t)s0 * HC);
            uint2 u1 = *(const uint2*)(hs + (size_t)s1 * HC);
            uint2 u2 = *(const uint2*)(hs + (size_t)s2 * HC);
            uint2 u3 = *(const uint2*)(hs + (size_t)s3 * HC);
            f32x4 a0 = fp8x4_to_f32(u0.x), b0 = fp8x4_to_f32(u0.y);
            f32x4 a1 = fp8x4_to_f32(u1.x), b1 = fp8x4_to_f32(u1.y);
            f32x4 a2 = fp8x4_to_f32(u2.x), b2 = fp8x4_to_f32(u2.y);
            f32x4 a3 = fp8x4_to_f32(u3.x), b3 = fp8x4_to_f32(u3.y);
            #pragma unroll
            for (int k = 0; k < 4; ++k) {
                acc[k]     += w0 * a0[k];
                acc[k + 4] += w0 * b0[k];
                acc[k]     += w1 * a1[k];
                acc[k + 4] += w1 * b1[k];
                acc[k]     += w2 * a2[k];
                acc[k + 4] += w2 * b2[k];
                acc[k]     += w3 * a3[k];
                acc[k + 4] += w3 * b3[k];
            }
        }
        for (; e < hi; ++e) {
            int s0 = csr_sh[e - c0];
            float w0 = ew_sh[e - c0];
            uint2 u0 = *(const uint2*)(hs + (size_t)s0 * HC);
            f32x4 a0 = fp8x4_to_f32(u0.x), b0 = fp8x4_to_f32(u0.y);
            #pragma unroll
            for (int k = 0; k < 4; ++k) {
                acc[k]     += w0 * a0[k];
                acc[k + 4] += w0 * b0[k];
            }
        }
        __syncthreads();
    }

    float inv = dinv[n * 4 + head];
    bf16x8 o;
    #pragma unroll
    for (int k = 0; k < 8; ++k)
        o[k] = (__bf16)fmaxf(acc[k] * inv + bias_l[slice * 128 + ch * 8 + k], 0.f);
    *(bf16x8*)(outb + (size_t)n * HC + slice * 128 + ch * 8) = o;
}

// ---------------- global mean pool (race-free partials) ----------------

__device__ __forceinline__ int lower_bound_batch(const int* __restrict__ batch, int val) {
    int lo = 0, hi = Nn;
    while (lo < hi) { int mid = (lo + hi) >> 1; if (batch[mid] < val) lo = mid + 1; else hi = mid; }
    return lo;
}

__global__ void pool_kernel(const __bf16* __restrict__ h2b, const int* __restrict__ batch,
                            float* __restrict__ pooledP) {
    int b = blockIdx.x, part = blockIdx.y;   // grid (B, 8)
    int tid = threadIdx.x;
    int start = lower_bound_batch(batch, b);
    int end   = lower_bound_batch(batch, b + 1);
    int len = end - start;
    int chunk = (len + 7) / 8;
    int s0 = start + part * chunk;
    int s1 = min(s0 + chunk, end);
    float acc[4] = {0.f, 0.f, 0.f, 0.f};
    for (int n = s0; n < s1; ++n) {
        bf16x4 v = ((const bf16x4*)(h2b + (size_t)n * HC))[tid];
        #pragma unroll
        for (int k = 0; k < 4; ++k) acc[k] += (float)v[k];
    }
    #pragma unroll
    for (int k = 0; k < 4; ++k)
        pooledP[((size_t)part * Bb + b) * HC + tid * 4 + k] = acc[k];
}

// ---------------- projection (k-split, race-free partials) + layernorm ----------------

__global__ __launch_bounds__(512) void proj_partial_kernel(const float* __restrict__ pooledP,
                                                           const int* __restrict__ batch,
                                                           const float* __restrict__ projW,
                                                           float* __restrict__ projP) {
    int b = blockIdx.x, part = blockIdx.y;   // grid (16, 8)
    int d = threadIdx.x;                     // 512
    __shared__ float psum[HC];
    int start = lower_bound_batch(batch, b);
    int end   = lower_bound_batch(batch, b + 1);
    float inv = 1.0f / fmaxf((float)(end - start), 1.0f);
    for (int k = d; k < HC; k += 512) {
        float s = 0.f;
        #pragma unroll
        for (int p = 0; p < 8; ++p) s += pooledP[((size_t)p * Bb + b) * HC + k];
        psum[k] = s * inv;
    }
    __syncthreads();
    float acc = 0.f;
    int k0 = part * 128;
    for (int k = k0; k < k0 + 128; ++k)
        acc += psum[k] * projW[(size_t)k * Dd + d];
    projP[((size_t)part * Bb + b) * Dd + d] = acc;
}

__global__ __launch_bounds__(512) void ln_kernel(const float* __restrict__ projP,
                                                 const float* __restrict__ projb,
                                                 const float* __restrict__ gamma,
                                                 const float* __restrict__ beta,
                                                 float* __restrict__ out) {
    int b = blockIdx.x;
    int d = threadIdx.x;
    __shared__ float red[512];
    float o = projb[d];
    #pragma unroll
    for (int p = 0; p < 8; ++p) o += projP[((size_t)p * Bb + b) * Dd + d];
    red[d] = o;
    __syncthreads();
    for (int off = 256; off > 0; off >>= 1) {
        if (d < off) red[d] += red[d + off];
        __syncthreads();
    }
    float mu = red[0] / (float)Dd;
    __syncthreads();
    float df = o - mu;
    red[d] = df * df;
    __syncthreads();
    for (int off = 256; off > 0; off >>= 1) {
        if (d < off) red[d] += red[d + off];
        __syncthreads();
    }
    float var = red[0] / (float)Dd;
    out[b * Dd + d] = df / sqrtf(var + LN_EPS) * gamma[d] + beta[d];
}

// ---------------- launch ----------------

extern "C" void kernel_launch(void* const* d_in, const int* in_sizes, int n_in,
                              void* d_out, int out_size, void* d_ws, size_t ws_size,
                              hipStream_t stream) {
    const float* x         = (const float*)d_in[0];
    const int*   ei        = (const int*)d_in[1];
    const int*   batch     = (const int*)d_in[2];
    const float* W0        = (const float*)d_in[3];
    const float* W_rest    = (const float*)d_in[4];
    const float* att_src   = (const float*)d_in[5];
    const float* att_dst   = (const float*)d_in[6];
    const float* conv_bias = (const float*)d_in[7];
    const float* proj_W    = (const float*)d_in[8];
    const float* proj_b    = (const float*)d_in[9];
    const float* ln_gamma  = (const float*)d_in[10];
    const float* ln_beta   = (const float*)d_in[11];
    float* out = (float*)d_out;

    char* ws = (char*)d_ws;
    size_t off = 0;
    auto alloc = [&](size_t bytes) {
        void* p = ws + off;
        off = (off + bytes + 255) & ~(size_t)255;
        return p;
    };
    unsigned char* h8 = (unsigned char*)alloc((size_t)Nn * HC);   // GEMM out (fp8, agg payload)
    __bf16* h2b     = (__bf16*)alloc((size_t)Nn * HC * 2);        // layer out (bf16)
    __bf16* xb      = (__bf16*)alloc((size_t)Nn * Dd * 2);
    __bf16* W0T     = (__bf16*)alloc((size_t)HC * Dd * 2);
    __bf16* WrT     = (__bf16*)alloc((size_t)3 * HC * HC * 2);
    float*  aprt_s  = (float*)alloc((size_t)4 * Nn * Hh * 4);     // alpha partials
    float*  aprt_d  = (float*)alloc((size_t)4 * Nn * Hh * 4);
    float*  asrc    = (float*)alloc((size_t)Nn * Hh * 4);
    float*  adst    = (float*)alloc((size_t)Nn * Hh * 4);
    float*  ewT     = (float*)alloc((size_t)Hh * ETOT * 4);       // head-major
    float*  dinv    = (float*)alloc((size_t)Nn * Hh * 4);
    int*    deg     = (int*)alloc((size_t)Nn * 4);
    int*    tmp     = (int*)alloc((size_t)Nn * 4);
    int*    bsum    = (int*)alloc((size_t)256 * 4);
    int*    row_ptr = (int*)alloc((size_t)(Nn + 1) * 4);
    int*    cursor  = (int*)alloc((size_t)Nn * 4);
    int*    csr_src = (int*)alloc((size_t)ETOT * 4);
    float*  pooledP = (float*)alloc((size_t)8 * Bb * HC * 4);
    float*  projP   = (float*)alloc((size_t)8 * Bb * Dd * 4);
    (void)ws_size; (void)in_sizes; (void)n_in; (void)out_size;

    // ---- build CSR by destination ----
    hipMemsetAsync(deg, 0, (size_t)Nn * 4, stream);
    count_deg_kernel<<<(ETOT + 255) / 256, 256, 0, stream>>>(ei, deg);
    scan1_kernel<<<NBLK, 256, 0, stream>>>(deg, tmp, bsum);
    scan2_kernel<<<1, 256, 0, stream>>>(bsum);
    scan3_kernel<<<NBLK, 256, 0, stream>>>(tmp, bsum, deg, row_ptr, cursor);
    scatter_kernel<<<(ETOT + 255) / 256, 256, 0, stream>>>(ei, cursor, csr_src);

    // ---- bf16 casts / weight transposes ----
    cast_kernel<<<(Nn * Dd / 4 + 255) / 256, 256, 0, stream>>>(x, xb, Nn * Dd / 4);
    transpose_cast_kernel<<<dim3(HC / 32, Dd / 32, 1), dim3(32, 8), 0, stream>>>(W0, W0T, Dd, HC);
    transpose_cast_kernel<<<dim3(HC / 32, HC / 32, 3), dim3(32, 8), 0, stream>>>(W_rest, WrT, HC, HC);

    // ---- GAT layers ----
    dim3 gemm_grid(8, 160);   // 1280 swizzled ids -> (157 row-blocks, 8 col-blocks)
    for (int l = 0; l < Ll; ++l) {
        const __bf16* Afeat = (l == 0) ? xb : h2b;
        int K = (l == 0) ? Dd : HC;
        const __bf16* BT = (l == 0) ? W0T : (WrT + (size_t)(l - 1) * HC * HC);
        mfma_gemm_kernel<<<gemm_grid, 256, 0, stream>>>(
            Afeat, BT, h8, att_src + l * HC, att_dst + l * HC, aprt_s, aprt_d, Nn, K);
        alpha_sum_kernel<<<NBLK, 256, 0, stream>>>(aprt_s, aprt_d, asrc, adst);
        ew_kernel<<<(Nn + 3) / 4, 256, 0, stream>>>(asrc, adst, row_ptr, csr_src, ewT, dinv);
        agg_slice_kernel<<<dim3(8, Nn / 16), 256, 0, stream>>>(
            h8, ewT, dinv, row_ptr, csr_src, conv_bias + l * HC, h2b);
    }

    // ---- pool + proj + layernorm (all race-free partials, no memsets) ----
    pool_kernel<<<dim3(Bb, 8), 256, 0, stream>>>(h2b, batch, pooledP);
    proj_partial_kernel<<<dim3(Bb, 8), 512, 0, stream>>>(pooledP, batch, proj_W, projP);
    ln_kernel<<<Bb, 512, 0, stream>>>(projP, proj_b, ln_gamma, ln_beta, out);
}

// Round 5
// 629.184 us; speedup vs baseline: 1.1476x; 1.0410x over previous
//
#include <hip/hip_runtime.h>
#include <hip/hip_bf16.h>
#include <hip/hip_fp8.h>
#include <math.h>

#define Nn 20000
#define Ee 320000
#define Dd 512
#define Hh 4
#define Cc 256
#define Ll 4
#define Bb 16
#define HC 1024               // H*C
#define ETOT (Ee + Nn)        // edges + self loops = 340000
#define NEG_SLOPE 0.2f
#define LN_EPS 1e-5f
#define NBLK ((Nn + 255) / 256)   // 79 scan blocks

typedef __attribute__((ext_vector_type(8))) __bf16 bf16x8;
typedef __attribute__((ext_vector_type(4))) __bf16 bf16x4;
typedef __attribute__((ext_vector_type(4))) float f32x4;
typedef __attribute__((ext_vector_type(2))) float f32x2;

// fp8 e4m3 (OCP) x4 decode — HW packed cvt if available
__device__ __forceinline__ f32x4 fp8x4_to_f32(unsigned int v) {
#if __has_builtin(__builtin_amdgcn_cvt_pk_f32_fp8)
    f32x2 lo = __builtin_amdgcn_cvt_pk_f32_fp8((int)v, false);
    f32x2 hi = __builtin_amdgcn_cvt_pk_f32_fp8((int)v, true);
    f32x4 r; r[0] = lo[0]; r[1] = lo[1]; r[2] = hi[0]; r[3] = hi[1];
    return r;
#else
    f32x4 r;
    #pragma unroll
    for (int i = 0; i < 4; ++i) {
        __hip_fp8_e4m3 q; q.__x = (v >> (8 * i)) & 0xff;
        r[i] = (float)q;
    }
    return r;
#endif
}

__device__ __forceinline__ unsigned char f32_to_fp8(float f) {
    return __hip_fp8_e4m3(f).__x;
}

// ---------------- CSR build ----------------

__device__ __forceinline__ void decode_edge(const int* ei, int e, int& s, int& d) {
    if (e < Ee) { s = ei[e]; d = ei[Ee + e]; }
    else        { s = e - Ee; d = e - Ee; }   // self loop
}

__global__ void count_deg_kernel(const int* __restrict__ ei, int* __restrict__ deg) {
    int e = blockIdx.x * blockDim.x + threadIdx.x;
    if (e >= ETOT) return;
    int s, d; decode_edge(ei, e, s, d);
    atomicAdd(&deg[d], 1);
}

__global__ void scan1_kernel(const int* __restrict__ deg, int* __restrict__ tmp,
                             int* __restrict__ bsum) {
    __shared__ int sd[256];
    int tid = threadIdx.x;
    int i = blockIdx.x * 256 + tid;
    sd[tid] = (i < Nn) ? deg[i] : 0;
    __syncthreads();
    for (int off = 1; off < 256; off <<= 1) {
        int t = (tid >= off) ? sd[tid - off] : 0;
        __syncthreads();
        sd[tid] += t;
        __syncthreads();
    }
    if (i < Nn) tmp[i] = sd[tid];
    if (tid == 255) bsum[blockIdx.x] = sd[255];
}

__global__ void scan2_kernel(int* __restrict__ bsum) {   // single block, NBLK<=256
    __shared__ int sd[256];
    int tid = threadIdx.x;
    sd[tid] = (tid < NBLK) ? bsum[tid] : 0;
    __syncthreads();
    for (int off = 1; off < 256; off <<= 1) {
        int t = (tid >= off) ? sd[tid - off] : 0;
        __syncthreads();
        sd[tid] += t;
        __syncthreads();
    }
    if (tid < NBLK) bsum[tid] = sd[tid];
}

__global__ void scan3_kernel(const int* __restrict__ tmp, const int* __restrict__ bsum,
                             const int* __restrict__ deg,
                             int* __restrict__ row_ptr, int* __restrict__ cursor) {
    int i = blockIdx.x * 256 + threadIdx.x;
    if (i >= Nn) return;
    int boff = (blockIdx.x == 0) ? 0 : bsum[blockIdx.x - 1];
    int incl = tmp[i] + boff;
    row_ptr[i + 1] = incl;
    cursor[i] = incl - deg[i];
    if (i == 0) row_ptr[0] = 0;
}

__global__ void scatter_kernel(const int* __restrict__ ei, int* __restrict__ cursor,
                               int* __restrict__ csr_src) {
    int e = blockIdx.x * blockDim.x + threadIdx.x;
    if (e >= ETOT) return;
    int s, d; decode_edge(ei, e, s, d);
    int pos = atomicAdd(&cursor[d], 1);
    csr_src[pos] = s;
}

// ---------------- casts ----------------

__global__ void cast_kernel(const float* __restrict__ in, __bf16* __restrict__ out, int n4) {
    int i = blockIdx.x * blockDim.x + threadIdx.x;
    if (i >= n4) return;
    f32x4 v = ((const f32x4*)in)[i];
    bf16x4 o;
    #pragma unroll
    for (int k = 0; k < 4; ++k) o[k] = (__bf16)v[k];
    ((bf16x4*)out)[i] = o;
}

// W[K][N] fp32 -> WT[N][K] bf16; grid.z selects matrix (stride K*N)
__global__ void transpose_cast_kernel(const float* __restrict__ W, __bf16* __restrict__ WT,
                                      int K, int N) {
    __shared__ float tile[32][33];
    W  += (size_t)blockIdx.z * K * N;
    WT += (size_t)blockIdx.z * K * N;
    int n0 = blockIdx.x * 32, k0 = blockIdx.y * 32;
    for (int i = threadIdx.y; i < 32; i += 8)
        tile[i][threadIdx.x] = W[(size_t)(k0 + i) * N + n0 + threadIdx.x];
    __syncthreads();
    for (int i = threadIdx.y; i < 32; i += 8)
        WT[(size_t)(n0 + i) * K + k0 + threadIdx.x] = (__bf16)tile[threadIdx.x][i];
}

// ---------------- MFMA GEMM + fused alpha epilogue (r0 VERBATIM — proven 65us) ----------
// C8[M,1024](fp8) = A[M,K](bf16) @ BT[1024,K]^T. XCD swizzle (r11: FETCH 162->34MB).
// r18 note: r15/r16/r17 all tried intra-block pipelining (counted vmcnt, deep
// buffers, issue-early dbuf) and ALL regressed (98/83/77us vs 65us): every scheme
// grew LDS and traded away co-resident blocks; inter-block overlap (m114) beats
// intra-block pipelining here. This 32KB-LDS stage->sync->compute->sync structure
// at 2+ blocks/CU is the empirical local optimum — do not touch without new
// counter evidence. (r18 bench re-confirmed: 66us, MfmaUtil 25-26%, FETCH 34.8MB.)
// Epilogue computes alpha partials ps/pd from IN-REGISTER h (zero extra traffic).
// Race-free: part=(cblk&1)*2+(wave&1) — for fixed (row,head) the 4 writers
// (cblk in {2h,2h+1} x wave&1) get distinct parts. No atomics, no pre-zeroing.

__device__ __forceinline__ void async16(const __bf16* g, __bf16* l) {
    __builtin_amdgcn_global_load_lds((const __attribute__((address_space(1))) void*)g,
                                     (__attribute__((address_space(3))) void*)l,
                                     16, 0, 0);
}

__global__ __launch_bounds__(256) void mfma_gemm_kernel(
    const __bf16* __restrict__ A,   // [M][K]
    const __bf16* __restrict__ BT,  // [1024][K]
    unsigned char* __restrict__ C8, // [M][1024] fp8 e4m3 (agg gather payload)
    const float* __restrict__ att_s,  // [4][256] this layer
    const float* __restrict__ att_d,  // [4][256]
    float* __restrict__ aprt_s,     // [4][M][4] partials (race-free)
    float* __restrict__ aprt_d,     // [4][M][4]
    int M, int K)
{
    int lin = blockIdx.y * 8 + blockIdx.x;          // grid (8, 160) -> 1280 ids
    int rblk = (lin >> 6) * 8 + (lin & 7);
    int cblk = (lin >> 3) & 7;
    int rowBase = rblk * 128, colBase = cblk * 128;
    if (rowBase >= M) return;

    __shared__ __bf16 As[2][128 * 32];
    __shared__ __bf16 Bs[2][128 * 32];
    int tid = threadIdx.x;
    int wave = tid >> 6, lane = tid & 63;
    int m16 = lane & 15, quad = lane >> 4;
    int waveRow = (wave >> 1) * 64, waveCol = (wave & 1) * 64;

    f32x4 acc[4][4] = {};

    int srow = wave * 32 + (lane >> 2);          // staging row, +16 for second half
    int gch0 = (lane & 3) ^ ((srow >> 1) & 3);
    int gch1 = (lane & 3) ^ (((srow + 16) >> 1) & 3);
    int gr0 = rowBase + srow;       if (gr0 >= M) gr0 = M - 1;
    int gr1 = rowBase + srow + 16;  if (gr1 >= M) gr1 = M - 1;
    int ldsOff = srow * 32 + (lane & 3) * 8;

    for (int k0 = 0; k0 < K; k0 += 64) {
        #pragma unroll
        for (int p = 0; p < 2; ++p) {
            int kp = k0 + p * 32;
            async16(A + (size_t)gr0 * K + kp + gch0 * 8, &As[p][ldsOff]);
            async16(A + (size_t)gr1 * K + kp + gch1 * 8, &As[p][ldsOff + 16 * 32]);
            async16(BT + (size_t)(colBase + srow) * K + kp + gch0 * 8, &Bs[p][ldsOff]);
            async16(BT + (size_t)(colBase + srow + 16) * K + kp + gch1 * 8, &Bs[p][ldsOff + 16 * 32]);
        }
        __syncthreads();
        #pragma unroll
        for (int p = 0; p < 2; ++p) {
            bf16x8 af[4], bfr[4];
            #pragma unroll
            for (int i = 0; i < 4; ++i) {
                int row = waveRow + i * 16 + m16;
                af[i] = *(const bf16x8*)&As[p][row * 32 + (quad ^ ((row >> 1) & 3)) * 8];
                int col = waveCol + i * 16 + m16;
                bfr[i] = *(const bf16x8*)&Bs[p][col * 32 + (quad ^ ((col >> 1) & 3)) * 8];
            }
            #pragma unroll
            for (int i = 0; i < 4; ++i)
                #pragma unroll
                for (int j = 0; j < 4; ++j)
                    acc[i][j] = __builtin_amdgcn_mfma_f32_16x16x32_bf16(af[i], bfr[j], acc[i][j], 0, 0, 0);
        }
        __syncthreads();
    }

    // att weights for this wave's 64-col span (single head: span never crosses 256)
    int cbase = colBase + waveCol;
    int head = cbase >> 8;
    int part = (cblk & 1) * 2 + (wave & 1);
    float as4[4], ad4[4];
    #pragma unroll
    for (int j = 0; j < 4; ++j) {
        int off = (cbase + j * 16 + m16) & 255;
        as4[j] = att_s[head * 256 + off];
        ad4[j] = att_d[head * 256 + off];
    }

    // fp8 stores (C/D layout: col=lane&15, row=quad*4+reg) + alpha partials
    #pragma unroll
    for (int i = 0; i < 4; ++i) {
        int r0 = rowBase + waveRow + i * 16 + quad * 4;
        #pragma unroll
        for (int r = 0; r < 4; ++r) {
            int row = r0 + r;
            float ps = 0.f, pd = 0.f;
            #pragma unroll
            for (int j = 0; j < 4; ++j) {
                float h = acc[i][j][r];
                ps += h * as4[j];
                pd += h * ad4[j];
                if (row < M)
                    C8[(size_t)row * HC + colBase + waveCol + j * 16 + m16] = f32_to_fp8(h);
            }
            #pragma unroll
            for (int off = 1; off < 16; off <<= 1) {
                ps += __shfl_xor(ps, off);
                pd += __shfl_xor(pd, off);
            }
            if (m16 == 0 && row < M) {
                aprt_s[((size_t)part * M + row) * 4 + head] = ps;
                aprt_d[((size_t)part * M + row) * 4 + head] = pd;
            }
        }
    }
}

// ---------------- alpha partial reduce: asrc/adst[n] = sum over 4 parts ----------------

__global__ void alpha_sum_kernel(const float* __restrict__ aprt_s,
                                 const float* __restrict__ aprt_d,
                                 float* __restrict__ asrc, float* __restrict__ adst) {
    int n = blockIdx.x * 256 + threadIdx.x;
    if (n >= Nn) return;
    f32x4 s = {0.f, 0.f, 0.f, 0.f}, d = {0.f, 0.f, 0.f, 0.f};
    #pragma unroll
    for (int p = 0; p < 4; ++p) {
        f32x4 vs = ((const f32x4*)aprt_s)[(size_t)p * Nn + n];
        f32x4 vd = ((const f32x4*)aprt_d)[(size_t)p * Nn + n];
        #pragma unroll
        for (int k = 0; k < 4; ++k) { s[k] += vs[k]; d[k] += vd[k]; }
    }
    ((f32x4*)asrc)[n] = s;
    ((f32x4*)adst)[n] = d;
}

// ---------------- edge-weight precompute (head-major output) ----------------
// r19: 16 lanes/node (was 64). Avg degree 17 => 64-lane waves ran at 27% lane
// utilization with 20000 wave-body executions; 16-lane groups give ~70% util and
// ~10000 wave-bodies (each wave serves 4 nodes concurrently). Reduction is a
// 4-step shfl_xor within the aligned 16-group. FP change: denominator tree order
// only (~1e-7 rel) — far below output tolerance scale.

__global__ __launch_bounds__(256) void ew_kernel(const float* __restrict__ asrc,
                                                 const float* __restrict__ adst,
                                                 const int* __restrict__ row_ptr,
                                                 const int* __restrict__ csr_src,
                                                 float* __restrict__ ewT,
                                                 float* __restrict__ dinv) {
    int grp = threadIdx.x >> 4, lane16 = threadIdx.x & 15;
    int n = blockIdx.x * 16 + grp;
    if (n >= Nn) return;
    int start = row_ptr[n], end = row_ptr[n + 1];
    f32x4 ad = ((const f32x4*)adst)[n];
    f32x4 d = {0.f, 0.f, 0.f, 0.f};
    for (int e = start + lane16; e < end; e += 16) {
        int s = csr_src[e];
        f32x4 as = ((const f32x4*)asrc)[s];
        #pragma unroll
        for (int k = 0; k < 4; ++k) {
            float z = as[k] + ad[k];
            z = (z > 0.f) ? z : NEG_SLOPE * z;
            float ex = __expf(z);
            ewT[(size_t)k * ETOT + e] = ex;
            d[k] += ex;
        }
    }
    #pragma unroll
    for (int off = 8; off > 0; off >>= 1) {
        #pragma unroll
        for (int k = 0; k < 4; ++k) d[k] += __shfl_xor(d[k], off);
    }
    if (lane16 == 0) {
        f32x4 iv;
        #pragma unroll
        for (int k = 0; k < 4; ++k) iv[k] = 1.f / (d[k] + 1e-16f);
        ((f32x4*)dinv)[n] = iv;
    }
}

// ---------------- sliced aggregation ----------------
// r19: 16B fp8 per thread (8 ch-threads x 32 node-slots; was 8B x 16). Per-edge
// lane-op redundancy (LDS reads, addr calc, load issue duplicated per ch-thread)
// drops ~33%; L2 line-requests/edge UNCHANGED (same 128B/slice footprint) — this
// cleanly discriminates instruction-bound vs L2-request-bound. (src,w) fused into
// one int2 => single ds_read_b64. 1024-edge chunks halve stage/sync rounds.
// Per-channel accumulation order stays ascending-e => bitwise identical.
// grid (8, 625): slice -> XCD affinity preserved (per-XCD footprint 2.5MB, r10).

__global__ __launch_bounds__(256) void agg_slice_kernel(
    const unsigned char* __restrict__ h8,
    const float* __restrict__ ewT,
    const float* __restrict__ dinv,
    const int* __restrict__ row_ptr,
    const int* __restrict__ csr_src,
    const float* __restrict__ bias_l,
    __bf16* __restrict__ outb)
{
    int slice = blockIdx.x;              // 0..7
    int head = slice >> 1;
    int tid = threadIdx.x;
    int nslot = tid >> 3;                // 0..31
    int ch = tid & 7;                    // 16B fp8 group within 128B slice
    int n = blockIdx.y * 32 + nslot;

    __shared__ int2 ce_sh[1024];         // (src, bitcast ew)
    __shared__ int  rp_sh[33];

    if (tid < 33) rp_sh[tid] = row_ptr[blockIdx.y * 32 + tid];
    __syncthreads();
    int blk_lo = rp_sh[0], blk_hi = rp_sh[32];
    int start = rp_sh[nslot], end = rp_sh[nslot + 1];

    const unsigned char* hs = h8 + slice * 128 + ch * 16;
    const float* ewh = ewT + (size_t)head * ETOT;
    float acc[16] = {};

    for (int c0 = blk_lo; c0 < blk_hi; c0 += 1024) {
        int c1 = min(c0 + 1024, blk_hi);
        int cnt = c1 - c0;
        for (int i = tid; i < cnt; i += 256) {     // coalesced stage
            int2 v;
            v.x = csr_src[c0 + i];
            v.y = __float_as_int(ewh[c0 + i]);
            ce_sh[i] = v;
        }
        __syncthreads();
        int lo = max(start, c0), hi = min(end, c1);
        for (int e = lo; e < hi; ++e) {
            int2 v = ce_sh[e - c0];
            float w = __int_as_float(v.y);
            uint4 u = *(const uint4*)(hs + (size_t)v.x * HC);
            f32x4 a0 = fp8x4_to_f32(u.x), a1 = fp8x4_to_f32(u.y);
            f32x4 a2 = fp8x4_to_f32(u.z), a3 = fp8x4_to_f32(u.w);
            #pragma unroll
            for (int k = 0; k < 4; ++k) {
                acc[k]      += w * a0[k];
                acc[k + 4]  += w * a1[k];
                acc[k + 8]  += w * a2[k];
                acc[k + 12] += w * a3[k];
            }
        }
        __syncthreads();
    }

    float inv = dinv[n * 4 + head];
    bf16x8 o0, o1;
    #pragma unroll
    for (int k = 0; k < 8; ++k) {
        o0[k] = (__bf16)fmaxf(acc[k] * inv + bias_l[slice * 128 + ch * 16 + k], 0.f);
        o1[k] = (__bf16)fmaxf(acc[k + 8] * inv + bias_l[slice * 128 + ch * 16 + 8 + k], 0.f);
    }
    *(bf16x8*)(outb + (size_t)n * HC + slice * 128 + ch * 16) = o0;
    *(bf16x8*)(outb + (size_t)n * HC + slice * 128 + ch * 16 + 8) = o1;
}

// ---------------- global mean pool (race-free partials) ----------------

__device__ __forceinline__ int lower_bound_batch(const int* __restrict__ batch, int val) {
    int lo = 0, hi = Nn;
    while (lo < hi) { int mid = (lo + hi) >> 1; if (batch[mid] < val) lo = mid + 1; else hi = mid; }
    return lo;
}

__global__ void pool_kernel(const __bf16* __restrict__ h2b, const int* __restrict__ batch,
                            float* __restrict__ pooledP) {
    int b = blockIdx.x, part = blockIdx.y;   // grid (B, 8)
    int tid = threadIdx.x;
    int start = lower_bound_batch(batch, b);
    int end   = lower_bound_batch(batch, b + 1);
    int len = end - start;
    int chunk = (len + 7) / 8;
    int s0 = start + part * chunk;
    int s1 = min(s0 + chunk, end);
    float acc[4] = {0.f, 0.f, 0.f, 0.f};
    for (int n = s0; n < s1; ++n) {
        bf16x4 v = ((const bf16x4*)(h2b + (size_t)n * HC))[tid];
        #pragma unroll
        for (int k = 0; k < 4; ++k) acc[k] += (float)v[k];
    }
    #pragma unroll
    for (int k = 0; k < 4; ++k)
        pooledP[((size_t)part * Bb + b) * HC + tid * 4 + k] = acc[k];
}

// ---------------- projection (k-split, race-free partials) + layernorm ----------------

__global__ __launch_bounds__(512) void proj_partial_kernel(const float* __restrict__ pooledP,
                                                           const int* __restrict__ batch,
                                                           const float* __restrict__ projW,
                                                           float* __restrict__ projP) {
    int b = blockIdx.x, part = blockIdx.y;   // grid (16, 8)
    int d = threadIdx.x;                     // 512
    __shared__ float psum[HC];
    int start = lower_bound_batch(batch, b);
    int end   = lower_bound_batch(batch, b + 1);
    float inv = 1.0f / fmaxf((float)(end - start), 1.0f);
    for (int k = d; k < HC; k += 512) {
        float s = 0.f;
        #pragma unroll
        for (int p = 0; p < 8; ++p) s += pooledP[((size_t)p * Bb + b) * HC + k];
        psum[k] = s * inv;
    }
    __syncthreads();
    float acc = 0.f;
    int k0 = part * 128;
    for (int k = k0; k < k0 + 128; ++k)
        acc += psum[k] * projW[(size_t)k * Dd + d];
    projP[((size_t)part * Bb + b) * Dd + d] = acc;
}

__global__ __launch_bounds__(512) void ln_kernel(const float* __restrict__ projP,
                                                 const float* __restrict__ projb,
                                                 const float* __restrict__ gamma,
                                                 const float* __restrict__ beta,
                                                 float* __restrict__ out) {
    int b = blockIdx.x;
    int d = threadIdx.x;
    __shared__ float red[512];
    float o = projb[d];
    #pragma unroll
    for (int p = 0; p < 8; ++p) o += projP[((size_t)p * Bb + b) * Dd + d];
    red[d] = o;
    __syncthreads();
    for (int off = 256; off > 0; off >>= 1) {
        if (d < off) red[d] += red[d + off];
        __syncthreads();
    }
    float mu = red[0] / (float)Dd;
    __syncthreads();
    float df = o - mu;
    red[d] = df * df;
    __syncthreads();
    for (int off = 256; off > 0; off >>= 1) {
        if (d < off) red[d] += red[d + off];
        __syncthreads();
    }
    float var = red[0] / (float)Dd;
    out[b * Dd + d] = df / sqrtf(var + LN_EPS) * gamma[d] + beta[d];
}

// ---------------- launch ----------------

extern "C" void kernel_launch(void* const* d_in, const int* in_sizes, int n_in,
                              void* d_out, int out_size, void* d_ws, size_t ws_size,
                              hipStream_t stream) {
    const float* x         = (const float*)d_in[0];
    const int*   ei        = (const int*)d_in[1];
    const int*   batch     = (const int*)d_in[2];
    const float* W0        = (const float*)d_in[3];
    const float* W_rest    = (const float*)d_in[4];
    const float* att_src   = (const float*)d_in[5];
    const float* att_dst   = (const float*)d_in[6];
    const float* conv_bias = (const float*)d_in[7];
    const float* proj_W    = (const float*)d_in[8];
    const float* proj_b    = (const float*)d_in[9];
    const float* ln_gamma  = (const float*)d_in[10];
    const float* ln_beta   = (const float*)d_in[11];
    float* out = (float*)d_out;

    char* ws = (char*)d_ws;
    size_t off = 0;
    auto alloc = [&](size_t bytes) {
        void* p = ws + off;
        off = (off + bytes + 255) & ~(size_t)255;
        return p;
    };
    unsigned char* h8 = (unsigned char*)alloc((size_t)Nn * HC);   // GEMM out (fp8, agg payload)
    __bf16* h2b     = (__bf16*)alloc((size_t)Nn * HC * 2);        // layer out (bf16)
    __bf16* xb      = (__bf16*)alloc((size_t)Nn * Dd * 2);
    __bf16* W0T     = (__bf16*)alloc((size_t)HC * Dd * 2);
    __bf16* WrT     = (__bf16*)alloc((size_t)3 * HC * HC * 2);
    float*  aprt_s  = (float*)alloc((size_t)4 * Nn * Hh * 4);     // alpha partials
    float*  aprt_d  = (float*)alloc((size_t)4 * Nn * Hh * 4);
    float*  asrc    = (float*)alloc((size_t)Nn * Hh * 4);
    float*  adst    = (float*)alloc((size_t)Nn * Hh * 4);
    float*  ewT     = (float*)alloc((size_t)Hh * ETOT * 4);       // head-major
    float*  dinv    = (float*)alloc((size_t)Nn * Hh * 4);
    int*    deg     = (int*)alloc((size_t)Nn * 4);
    int*    tmp     = (int*)alloc((size_t)Nn * 4);
    int*    bsum    = (int*)alloc((size_t)256 * 4);
    int*    row_ptr = (int*)alloc((size_t)(Nn + 1) * 4);
    int*    cursor  = (int*)alloc((size_t)Nn * 4);
    int*    csr_src = (int*)alloc((size_t)ETOT * 4);
    float*  pooledP = (float*)alloc((size_t)8 * Bb * HC * 4);
    float*  projP   = (float*)alloc((size_t)8 * Bb * Dd * 4);
    (void)ws_size; (void)in_sizes; (void)n_in; (void)out_size;

    // ---- build CSR by destination ----
    hipMemsetAsync(deg, 0, (size_t)Nn * 4, stream);
    count_deg_kernel<<<(ETOT + 255) / 256, 256, 0, stream>>>(ei, deg);
    scan1_kernel<<<NBLK, 256, 0, stream>>>(deg, tmp, bsum);
    scan2_kernel<<<1, 256, 0, stream>>>(bsum);
    scan3_kernel<<<NBLK, 256, 0, stream>>>(tmp, bsum, deg, row_ptr, cursor);
    scatter_kernel<<<(ETOT + 255) / 256, 256, 0, stream>>>(ei, cursor, csr_src);

    // ---- bf16 casts / weight transposes ----
    cast_kernel<<<(Nn * Dd / 4 + 255) / 256, 256, 0, stream>>>(x, xb, Nn * Dd / 4);
    transpose_cast_kernel<<<dim3(HC / 32, Dd / 32, 1), dim3(32, 8), 0, stream>>>(W0, W0T, Dd, HC);
    transpose_cast_kernel<<<dim3(HC / 32, HC / 32, 3), dim3(32, 8), 0, stream>>>(W_rest, WrT, HC, HC);

    // ---- GAT layers ----
    dim3 gemm_grid(8, 160);   // 1280 swizzled ids -> (157 row-blocks, 8 col-blocks)
    for (int l = 0; l < Ll; ++l) {
        const __bf16* Afeat = (l == 0) ? xb : h2b;
        int K = (l == 0) ? Dd : HC;
        const __bf16* BT = (l == 0) ? W0T : (WrT + (size_t)(l - 1) * HC * HC);
        mfma_gemm_kernel<<<gemm_grid, 256, 0, stream>>>(
            Afeat, BT, h8, att_src + l * HC, att_dst + l * HC, aprt_s, aprt_d, Nn, K);
        alpha_sum_kernel<<<NBLK, 256, 0, stream>>>(aprt_s, aprt_d, asrc, adst);
        ew_kernel<<<(Nn + 15) / 16, 256, 0, stream>>>(asrc, adst, row_ptr, csr_src, ewT, dinv);
        agg_slice_kernel<<<dim3(8, Nn / 32), 256, 0, stream>>>(
            h8, ewT, dinv, row_ptr, csr_src, conv_bias + l * HC, h2b);
    }

    // ---- pool + proj + layernorm (all race-free partials, no memsets) ----
    pool_kernel<<<dim3(Bb, 8), 256, 0, stream>>>(h2b, batch, pooledP);
    proj_partial_kernel<<<dim3(Bb, 8), 512, 0, stream>>>(pooledP, batch, proj_W, projP);
    ln_kernel<<<Bb, 512, 0, stream>>>(projP, proj_b, ln_gamma, ln_beta, out);
}